// Round 5
// baseline (596.773 us; speedup 1.0000x reference)
//
#include <hip/hip_runtime.h>
#include <hip/hip_bf16.h>

// Problem constants (B,L,D)=(4,2048,768), K=12, M=1, CK=4, H=64
#define B_       4
#define L_       2048
#define D_       768
#define K_       12
#define H_       64
#define CK_      4
#define DIM_MEM_ 768
#define DMK      780        // DIM_MEM + K
#define NT       (B_*L_)    // 8192 tokens
#define NSUM     1536       // 2*K*H  (summary width)
#define NACT     2304       // K*192  (y_act width)
#define NCHUNK   16
#define CHLEN    (L_/NCHUNK)  // 128
#define PSTRIDE  132

typedef __attribute__((ext_vector_type(8))) short          bf16x8;
typedef __attribute__((ext_vector_type(8))) unsigned short u16x8;
typedef __attribute__((ext_vector_type(4))) float          f32x4;

__device__ __forceinline__ ushort f2bf(float v) {
    __hip_bfloat16 h = __float2bfloat16(v);
    return *reinterpret_cast<ushort*>(&h);
}
// fast tanh via hw exp; safe for any x
__device__ __forceinline__ float tanh_fast(float x) {
    float t = __expf(-2.f * fabsf(x));
    float r = (1.f - t) / (1.f + t);
    return copysignf(r, x);
}

// ---------------------------------------------------------------------------
// Merged prep: transpose-cast jobs (32x32 LDS tiles) + x->bf16 cast.
// remap==1: interleaved val/gate layout for the fused spectral GEMM:
//   virtual col vc: grp=vc>>5, which=(vc>>4)&1, nn=grp*16+(vc&15)
//   orig col = colbase + (nn/192)*384 + which*192 + (nn%192)
// ---------------------------------------------------------------------------
struct PrepJobs {
    const float* W[6];
    ushort*      out[6];
    int ldw[6], Kd[6], colbase[6], remap[6], ntx[6];
    int start[7];
    const float* cast_in;
    ushort*      cast_out;
    int n4;
};

__global__ __launch_bounds__(256)
void prep_all(PrepJobs J)
{
    int blk = blockIdx.x;
    if (blk >= J.start[6]) {                       // cast job
        int i = (blk - J.start[6]) * 256 + threadIdx.x;
        if (i < J.n4) {
            float4 v = reinterpret_cast<const float4*>(J.cast_in)[i];
            ushort4 o;
            o.x = f2bf(v.x); o.y = f2bf(v.y); o.z = f2bf(v.z); o.w = f2bf(v.w);
            reinterpret_cast<ushort4*>(J.cast_out)[i] = o;
        }
        return;
    }
    int j = 0;
    while (blk >= J.start[j + 1]) ++j;
    int rel = blk - J.start[j];
    int ntx = J.ntx[j];
    int n0 = (rel % ntx) * 32, k0 = (rel / ntx) * 32;
    const float* W = J.W[j];
    int ldw = J.ldw[j], Kd = J.Kd[j], colbase = J.colbase[j], remap = J.remap[j];
    ushort* out = J.out[j];

    __shared__ float tile[32][33];
    int tx = threadIdx.x & 31, ty = threadIdx.x >> 5;
    int n = n0 + tx;
    int c;
    if (remap) {
        int grp = n >> 5, which = (n >> 4) & 1, nn = (grp << 4) + (n & 15);
        c = colbase + (nn / 192) * 384 + which * 192 + (nn % 192);
    } else {
        c = colbase + n;
    }
    #pragma unroll
    for (int r = 0; r < 4; ++r)
        tile[ty + r*8][tx] = W[(size_t)(k0 + ty + r*8) * ldw + c];
    __syncthreads();
    #pragma unroll
    for (int r = 0; r < 4; ++r)
        out[(size_t)(n0 + ty + r*8) * Kd + k0 + tx] = f2bf(tile[tx][ty + r*8]);
}

// ---------------------------------------------------------------------------
// bf16 MFMA GEMM: C[M,N] fp32 = A[M,K] * BT[Nr,K]^T, write guard col<N.
// 128x128 tile, BK=64, 4 waves each 64x64. PROVEN sync discipline only.
// ---------------------------------------------------------------------------
__global__ __launch_bounds__(256)
void gemm_bf16_mfma(const ushort* __restrict__ A, const ushort* __restrict__ BT,
                    float* __restrict__ C, int Kd, int N, int ldc)
{
    __shared__ ushort As[128*64];   // 16 KB
    __shared__ ushort Bs[128*64];   // 16 KB
    int tid = threadIdx.x, lane = tid & 63;
    int lr = lane & 15, quad = lane >> 4;
    int wave = tid >> 6;
    int wr = (wave >> 1) * 64, wc = (wave & 1) * 64;
    int m0 = blockIdx.y * 128, n0 = blockIdx.x * 128;

    f32x4 acc[4][4] = {};

    int srow = tid >> 3;                       // 0..31
    int tc   = tid & 7;                        // logical k-chunk (8B*2=16B)
    const ushort* gA = A  + (size_t)(m0 + srow) * Kd + tc * 8;
    const ushort* gB = BT + (size_t)(n0 + srow) * Kd + tc * 8;
    int woff = srow * 64 + ((tc ^ (srow & 7)) * 8);
    int rx = lr & 7;

    for (int k0 = 0; k0 < Kd; k0 += 64) {
        u16x8 a[4], b[4];
        #pragma unroll
        for (int p = 0; p < 4; ++p) {
            a[p] = *reinterpret_cast<const u16x8*>(gA + (size_t)(32*p) * Kd);
            b[p] = *reinterpret_cast<const u16x8*>(gB + (size_t)(32*p) * Kd);
        }
        gA += 64; gB += 64;
        __syncthreads();               // prev iteration's LDS reads complete
        #pragma unroll
        for (int p = 0; p < 4; ++p) {
            *reinterpret_cast<u16x8*>(As + woff + p*2048) = a[p];
            *reinterpret_cast<u16x8*>(Bs + woff + p*2048) = b[p];
        }
        __syncthreads();               // staging visible to all waves
        #pragma unroll
        for (int ks = 0; ks < 2; ++ks) {
            bf16x8 af[4], bf[4];
            #pragma unroll
            for (int i = 0; i < 4; ++i) {
                int ca = ((ks*4 + quad) ^ rx) * 8;
                af[i] = *reinterpret_cast<const bf16x8*>(As + (wr + i*16 + lr) * 64 + ca);
                bf[i] = *reinterpret_cast<const bf16x8*>(Bs + (wc + i*16 + lr) * 64 + ca);
            }
            #pragma unroll
            for (int i = 0; i < 4; ++i)
                #pragma unroll
                for (int j = 0; j < 4; ++j)
                    acc[i][j] = __builtin_amdgcn_mfma_f32_16x16x32_bf16(
                                    af[i], bf[j], acc[i][j], 0, 0, 0);
        }
    }

    #pragma unroll
    for (int i = 0; i < 4; ++i)
        #pragma unroll
        for (int j = 0; j < 4; ++j)
            #pragma unroll
            for (int r = 0; r < 4; ++r) {
                int row = m0 + wr + i*16 + quad*4 + r;      // m89-verified C/D map
                int col = n0 + wc + j*16 + lr;
                if (col < N)
                    C[(size_t)row * ldc + col] = acc[i][j][r];
            }
}

// ---------------------------------------------------------------------------
// Fused spectral+skip GEMM, A-in-registers + B-in-LDS, 2 blocks/CU.
// r4 post-mortem: identical math/addressing PASSED but __launch_bounds__(256,2)
// pinned the allocator at 128 VGPR (4 waves/EU boundary) while live set is
// ~210 -> spill to scratch (WRITE_SIZE 37->81 MB, MfmaUtil 55->25%).
// Fix: (a) no occupancy clamp -- allocator sizes to pressure (~220 -> 2
// waves/EU; LDS 48 KB still gives 2 blocks/CU, same as r3); (b) j-loop split
// into two scoped 3-column halves so only bfr[3][2] (24 VGPR) is live at a
// time. Everything else byte-identical to the r4 proven-correct version.
// Queue discipline per body (computes tile t, PAR=t&1):
//   stage B(t+1) [6 gload_lds, buf PAR^1] ; sched_barrier(0) pins order ;
//   load A(t+1) frags [8 global b128 -> af_other] ; {3-col ds_read+MFMA} x2 ;
//   vmcnt(8) drains B(t+1), leaves A(t+1) in flight ; s_barrier.
// ---------------------------------------------------------------------------
#define GLOAD16(gp, dp) __builtin_amdgcn_global_load_lds( \
    (__attribute__((address_space(1))) const void*)(gp),  \
    (__attribute__((address_space(3))) void*)(dp), 16, 0, 0)

#define G2BODY(AF_USE, AF_LD, PAR, PREF, PA_NEXT, KDA, PB_NEXT, KDB)          \
  do {                                                                        \
    if (PREF) {                                                               \
        ushort* bd = lds + ((PAR)^1)*12288 + wave*512;                        \
        const ushort* bsrc = (PB_NEXT);                                       \
        _Pragma("unroll")                                                     \
        for (int s = 0; s < 6; ++s)                                           \
            GLOAD16(bsrc + (size_t)(32*s)*(KDB), bd + 2048*s);                \
        __builtin_amdgcn_sched_barrier(0);  /* pin queue order: B before A */ \
        const ushort* asrc = (PA_NEXT);                                       \
        _Pragma("unroll")                                                     \
        for (int i = 0; i < 4; ++i) {                                         \
            AF_LD[i][0] = *reinterpret_cast<const bf16x8*>(                   \
                              asrc + (size_t)(i*16)*(KDA));                   \
            AF_LD[i][1] = *reinterpret_cast<const bf16x8*>(                   \
                              asrc + (size_t)(i*16)*(KDA) + 32);              \
        }                                                                     \
    }                                                                         \
    const ushort* Bb = lds + (PAR)*12288;                                     \
    {   /* half 1: j = 0..2 (only 24 VGPR of B-frags live) */                 \
        bf16x8 bfr[3][2];                                                     \
        _Pragma("unroll")                                                     \
        for (int j = 0; j < 3; ++j) {                                         \
            const ushort* p = Bb + (wc + j*16 + lr) * 64;                     \
            bfr[j][0] = *reinterpret_cast<const bf16x8*>(p + ca0);            \
            bfr[j][1] = *reinterpret_cast<const bf16x8*>(p + ca1);            \
        }                                                                     \
        __builtin_amdgcn_s_setprio(1);                                        \
        _Pragma("unroll")                                                     \
        for (int ks = 0; ks < 2; ++ks)                                        \
            _Pragma("unroll")                                                 \
            for (int i = 0; i < 4; ++i)                                       \
                _Pragma("unroll")                                             \
                for (int j = 0; j < 3; ++j)                                   \
                    acc[i][j] = __builtin_amdgcn_mfma_f32_16x16x32_bf16(      \
                                    AF_USE[i][ks], bfr[j][ks], acc[i][j],     \
                                    0, 0, 0);                                 \
        __builtin_amdgcn_s_setprio(0);                                        \
    }                                                                         \
    {   /* half 2: j = 3..5 */                                                \
        bf16x8 bfr[3][2];                                                     \
        _Pragma("unroll")                                                     \
        for (int j = 0; j < 3; ++j) {                                         \
            const ushort* p = Bb + (wc + (3 + j)*16 + lr) * 64;               \
            bfr[j][0] = *reinterpret_cast<const bf16x8*>(p + ca0);            \
            bfr[j][1] = *reinterpret_cast<const bf16x8*>(p + ca1);            \
        }                                                                     \
        __builtin_amdgcn_s_setprio(1);                                        \
        _Pragma("unroll")                                                     \
        for (int ks = 0; ks < 2; ++ks)                                        \
            _Pragma("unroll")                                                 \
            for (int i = 0; i < 4; ++i)                                       \
                _Pragma("unroll")                                             \
                for (int j = 0; j < 3; ++j)                                   \
                    acc[i][3 + j] = __builtin_amdgcn_mfma_f32_16x16x32_bf16(  \
                                    AF_USE[i][ks], bfr[j][ks], acc[i][3 + j], \
                                    0, 0, 0);                                 \
        __builtin_amdgcn_s_setprio(0);                                        \
    }                                                                         \
    if (PREF) {                                                               \
        asm volatile("s_waitcnt vmcnt(8)" ::: "memory");                      \
        __builtin_amdgcn_s_barrier();                                         \
    }                                                                         \
  } while (0)

__global__ __launch_bounds__(256)
void gemm2_areg(const ushort* __restrict__ Sm, const ushort* __restrict__ Xb,
                const ushort* __restrict__ WsC, const ushort* __restrict__ WiC,
                ushort* __restrict__ yact)
{
    // LDS: B double-buffer only, 192x64 ushorts per buffer = 24 KB x2 = 48 KB
    __shared__ ushort lds[24576];
    const int tid  = threadIdx.x;
    const int lane = tid & 63, wave = tid >> 6;      // wave 0..3
    const int lr = lane & 15, quad = lane >> 4, rx = lr & 7;
    const int wr = (wave >> 1) * 64;     // 0,64
    const int wc = (wave & 1) * 96;      // 0,96
    const int m0 = blockIdx.y * 128, n0 = blockIdx.x * 192;

    // B staging source (pre-swizzled chunk): LDS[row][c] holds chunk c^(row&7)
    const int sr = tid >> 3;             // 0..31
    const int sc = (tid & 7) ^ (sr & 7);
    const ushort* pB1 = WsC + (size_t)(n0 + sr) * 1536 + sc * 8;
    const ushort* pB2 = WiC + (size_t)(n0 + sr) * 768  + sc * 8;

    // A direct-load per-lane row base (logical fragment address)
    const ushort* pA1 = Sm + (size_t)(m0 + wr + lr) * 1536 + quad * 8;
    const ushort* pA2 = Xb + (size_t)(m0 + wr + lr) * 768  + quad * 8;

    f32x4 acc[4][6] = {};
    bf16x8 af0[4][2], af1[4][2];
    const int ca0 = (quad ^ rx) * 8;
    const int ca1 = ((4 + quad) ^ rx) * 8;

    // prologue: stage B(0) [6], then A(0)->af0 [8]; vmcnt(8) drains B(0)
    {
        ushort* bd = lds + wave*512;
        #pragma unroll
        for (int s = 0; s < 6; ++s)
            GLOAD16(pB1 + (size_t)(32*s)*1536, bd + 2048*s);
        __builtin_amdgcn_sched_barrier(0);
        #pragma unroll
        for (int i = 0; i < 4; ++i) {
            af0[i][0] = *reinterpret_cast<const bf16x8*>(pA1 + (size_t)(i*16)*1536);
            af0[i][1] = *reinterpret_cast<const bf16x8*>(pA1 + (size_t)(i*16)*1536 + 32);
        }
        asm volatile("s_waitcnt vmcnt(8)" ::: "memory");
        __builtin_amdgcn_s_barrier();
    }

    // segment 1 interior: tiles 0..21 (11 pairs), all prefetch within seg1
    #pragma unroll 1
    for (int t = 0; t < 22; t += 2) {
        G2BODY(af0, af1, 0, true, pA1 + (t+1)*64, 1536, pB1 + (t+1)*64, 1536);
        G2BODY(af1, af0, 1, true, pA1 + (t+2)*64, 1536, pB1 + (t+2)*64, 1536);
    }
    // bridge pair: tiles 22,23 (prefetch 23=seg1, 24=seg2)
    G2BODY(af0, af1, 0, true, pA1 + 23*64, 1536, pB1 + 23*64, 1536);
    G2BODY(af1, af0, 1, true, pA2,          768, pB2,          768);
    // segment 2 interior: tiles 24..33 (5 pairs)
    #pragma unroll 1
    for (int t = 0; t < 10; t += 2) {
        G2BODY(af0, af1, 0, true, pA2 + (t+1)*64, 768, pB2 + (t+1)*64, 768);
        G2BODY(af1, af0, 1, true, pA2 + (t+2)*64, 768, pB2 + (t+2)*64, 768);
    }
    // final pair: tiles 34,35 (35 has no prefetch, no trailing wait/barrier)
    G2BODY(af0, af1, 0, true,  pA2 + 11*64, 768, pB2 + 11*64, 768);
    G2BODY(af1, af0, 1, false, pA2,         768, pB2,         768);

    // epilogue: lane-local (val,gate) pairs -> gated SiLU -> bf16
    const int vg0 = (n0 + wc) >> 5;
    #pragma unroll
    for (int i = 0; i < 4; ++i)
        #pragma unroll
        for (int p = 0; p < 3; ++p)
            #pragma unroll
            for (int r = 0; r < 4; ++r) {
                int row = m0 + wr + i*16 + quad*4 + r;      // m89-verified C/D map
                int col = (vg0 + p)*16 + lr;
                float v  = acc[i][2*p][r];
                float gt = acc[i][2*p + 1][r];
                float y = v * (gt / (1.f + __expf(-gt)));
                yact[(size_t)row * NACT + col] = f2bf(y);
            }
}

// ---------------------------------------------------------------------------
// Token-local: conv(CK=4)+SiLU+RMSNorm(H)+phase -> pw, re, im
// ---------------------------------------------------------------------------
__global__ __launch_bounds__(256)
void token_kernel(const float* __restrict__ zmem, const float* __restrict__ conv_w,
                  const float* __restrict__ rms_scale, const float* __restrict__ theta_raw,
                  const float* __restrict__ dslopes, const float* __restrict__ sscale,
                  const float* __restrict__ tscale,
                  float* __restrict__ pw, float* __restrict__ re, float* __restrict__ im)
{
    int t = blockIdx.x;
    int b = t >> 11;
    int l = t & (L_ - 1);
    int tid = threadIdx.x;
    int h = tid & 63, kg = tid >> 6;

    __shared__ float s_pw[K_];

    if (tid < K_) {
        float acc = 0.f;
        #pragma unroll
        for (int j = 0; j < CK_; ++j) {
            int ll = l - (CK_ - 1) + j;
            if (ll >= 0)
                acc += zmem[(size_t)(b*L_ + ll)*DMK + DIM_MEM_ + tid]
                     * conv_w[j*DMK + DIM_MEM_ + tid];
        }
        float s  = acc / (1.f + expf(-acc));
        float lp = sscale[tid] * s;
        lp = fminf(10.f, fmaxf(-10.f, lp));
        float slope = log1pf(expf(dslopes[tid]));
        s_pw[tid] = expf(lp - slope * (float)(L_ - 1 - l));
    }

    float kv[3];
    #pragma unroll
    for (int q = 0; q < 3; ++q) {
        int kk = kg + q*4;
        int c = kk*H_ + h;
        float acc = 0.f;
        #pragma unroll
        for (int j = 0; j < CK_; ++j) {
            int ll = l - (CK_ - 1) + j;
            if (ll >= 0)
                acc += zmem[(size_t)(b*L_ + ll)*DMK + c] * conv_w[j*DMK + c];
        }
        kv[q] = acc / (1.f + __expf(-acc));          // silu (hw exp)
    }
    __syncthreads();

    #pragma unroll
    for (int q = 0; q < 3; ++q) {
        int kk = kg + q*4;
        float v = kv[q];
        float ss = v * v;
        #pragma unroll
        for (int off = 32; off > 0; off >>= 1)
            ss += __shfl_xor(ss, off, 64);
        float kn = v * rsqrtf(ss * (1.f/64.f) + 1e-6f) * rms_scale[h];
        float th = 0.001f + 2.999f * (1.f / (1.f + __expf(-theta_raw[kk*H_ + h])));
        float phi = tanh_fast(kn * tscale[kk]) * th;
        float kvw = kn * s_pw[kk];
        re[(size_t)t*(K_*H_) + kk*H_ + h] = kvw * __cosf(phi);
        im[(size_t)t*(K_*H_) + kk*H_ + h] = kvw * __sinf(phi);
    }
    if (tid < K_) pw[(size_t)t*K_ + tid] = s_pw[tid];
}

// ---------------------------------------------------------------------------
// Chunked scan pass 1
// ---------------------------------------------------------------------------
__global__ __launch_bounds__(128)
void scan_sums(const float* __restrict__ pw, const float* __restrict__ re,
               const float* __restrict__ im, float* __restrict__ part)
{
    int blk = blockIdx.x;
    int chunk = blk & (NCHUNK - 1);
    int bk = blk >> 4;
    int k = bk % K_;
    int b = bk / K_;
    int tid = threadIdx.x;
    int h = tid & 63;
    const float* __restrict__ src = (tid >> 6) ? im : re;
    int l0 = chunk * CHLEN;

    size_t base  = ((size_t)(b*L_ + l0))*(K_*H_) + k*H_ + h;
    size_t dbase = ((size_t)(b*L_ + l0))*K_ + k;
    float s = 0.f, ds = 0.f;
    for (int i0 = 0; i0 < CHLEN; i0 += 8) {
        float v[8], d[8];
        #pragma unroll
        for (int j = 0; j < 8; ++j) {
            v[j] = src[base + (size_t)(i0 + j)*(K_*H_)];
            d[j] = pw [dbase + (size_t)(i0 + j)*K_];
        }
        #pragma unroll
        for (int j = 0; j < 8; ++j) { s += v[j]; ds += d[j]; }
    }
    size_t pb = ((size_t)bk * NCHUNK + chunk) * PSTRIDE;
    part[pb + tid] = s;
    if (tid == 0) part[pb + 128] = ds;
}

// ---------------------------------------------------------------------------
// Chunked scan pass 2: emit summary directly as bf16.
// ---------------------------------------------------------------------------
__global__ __launch_bounds__(128)
void scan_final(const float* __restrict__ pw, const float* __restrict__ re,
                const float* __restrict__ im, const float* __restrict__ part,
                ushort* __restrict__ summary)
{
    int blk = blockIdx.x;
    int chunk = blk & (NCHUNK - 1);
    int bk = blk >> 4;
    int k = bk % K_;
    int b = bk / K_;
    int tid = threadIdx.x;
    int h = tid & 63;
    int pi = tid >> 6;
    const float* __restrict__ src = pi ? im : re;
    int l0 = chunk * CHLEN;

    float acc = 0.f, dacc = 0.f;
    size_t pb0 = (size_t)bk * NCHUNK * PSTRIDE;
    for (int cn = 0; cn < chunk; ++cn) {
        acc  += part[pb0 + (size_t)cn*PSTRIDE + tid];
        dacc += part[pb0 + (size_t)cn*PSTRIDE + 128];
    }

    size_t base  = ((size_t)(b*L_ + l0))*(K_*H_) + k*H_ + h;
    size_t dbase = ((size_t)(b*L_ + l0))*K_ + k;
    int outch = 2*(k*H_ + h) + pi;
    for (int i0 = 0; i0 < CHLEN; i0 += 8) {
        float v[8], d[8];
        #pragma unroll
        for (int j = 0; j < 8; ++j) {
            v[j] = src[base + (size_t)(i0 + j)*(K_*H_)];
            d[j] = pw [dbase + (size_t)(i0 + j)*K_];
        }
        #pragma unroll
        for (int j = 0; j < 8; ++j) {
            acc += v[j]; dacc += d[j];
            float inv = 1.f / fmaxf(dacc, 1e-4f);
            summary[((size_t)(b*L_ + l0 + i0 + j))*NSUM + outch] = f2bf(acc * inv);
        }
    }
}

// ---------------------------------------------------------------------------
extern "C" void kernel_launch(void* const* d_in, const int* in_sizes, int n_in,
                              void* d_out, int out_size, void* d_ws, size_t ws_size,
                              hipStream_t stream)
{
    const float* x         = (const float*)d_in[0];
    const float* W_in      = (const float*)d_in[1];
    const float* conv_w    = (const float*)d_in[2];
    const float* rms_scale = (const float*)d_in[3];
    const float* theta_raw = (const float*)d_in[4];
    const float* dslopes   = (const float*)d_in[5];
    const float* sscale    = (const float*)d_in[6];
    const float* tscale    = (const float*)d_in[7];
    const float* W_sw      = (const float*)d_in[8];
    const float* W_out     = (const float*)d_in[9];
    float* out = (float*)d_out;
    char* ws   = (char*)d_ws;

    // Workspace (byte offsets, all 256-aligned). Peak ~115.4 MB (< proven 127).
    float*  zmem    = (float*) (ws + 0);           // NT*780 f32   = 25,559,040 B
    ushort* summary = (ushort*)(ws + 0);           // alias (zmem dead): 25,165,824 B
    float*  pw      = (float*) (ws + 25559040);    //   393,216 B
    float*  re      = (float*) (ws + 25952256);    // 25,165,824 B
    float*  im      = (float*) (ws + 51118080);    // 25,165,824 B
    ushort* yact    = (ushort*)(ws + 25952256);    // alias re+im (dead): 37,748,736 B
    float*  part    = (float*) (ws + 76283904);    //   405,504 B
    ushort* xb      = (ushort*)(ws + 76689408);    // 12,582,912 B
    ushort* WiCat   = (ushort*)(ws + 89272320);    //  7,077,888 B  [4608][768]  val/gate interleaved
    ushort* WsCat   = (ushort*)(ws + 96350208);    // 14,155,776 B  [4608][1536] val/gate interleaved
    ushort* WoT     = (ushort*)(ws + 110505984);   //  3,538,944 B  [768][2304]
    ushort* WimT    = (ushort*)(ws + 114044928);   //  1,376,256 B  [896][768] (pad)

    // ---- merged prep job table ----
    PrepJobs J{};
    J.W[0]=W_in;  J.out[0]=WiCat; J.ldw[0]=5388; J.Kd[0]=768;  J.colbase[0]=780; J.remap[0]=1; J.ntx[0]=144;
    J.W[1]=W_sw;  J.out[1]=WsCat; J.ldw[1]=4608; J.Kd[1]=1536; J.colbase[1]=0;   J.remap[1]=1; J.ntx[1]=144;
    J.W[2]=W_out; J.out[2]=WoT;   J.ldw[2]=768;  J.Kd[2]=2304; J.colbase[2]=0;   J.remap[2]=0; J.ntx[2]=24;
    J.W[3]=W_in;  J.out[3]=WimT;  J.ldw[3]=5388; J.Kd[3]=768;  J.colbase[3]=0;   J.remap[3]=0; J.ntx[3]=28;
    int tiles[4] = {144*24, 144*48, 24*72, 28*24};
    J.start[0] = 0;
    for (int j = 0; j < 4; ++j) J.start[j+1] = J.start[j] + tiles[j];
    J.start[5] = J.start[4];
    J.start[6] = J.start[4];
    J.cast_in = x; J.cast_out = xb; J.n4 = NT*D_/4;
    int nblk = J.start[6] + (J.n4 + 255)/256;

    dim3 blk(256);
    // 0) all preps in one launch
    prep_all<<<dim3(nblk), blk, 0, stream>>>(J);
    // 1) z_mem = x @ W_in[:, :780]  (bf16 MFMA, col-guarded at 780)
    gemm_bf16_mfma<<<dim3(7, 64), blk, 0, stream>>>(xb, WimT, zmem, 768, 780, 780);
    // 2) conv + silu + rmsnorm + phase
    token_kernel<<<dim3(NT), blk, 0, stream>>>(zmem, conv_w, rms_scale, theta_raw,
                                               dslopes, sscale, tscale, pw, re, im);
    // 3) chunked cumsum -> summary (bf16)
    scan_sums <<<dim3(B_*K_*NCHUNK), dim3(128), 0, stream>>>(pw, re, im, part);
    scan_final<<<dim3(B_*K_*NCHUNK), dim3(128), 0, stream>>>(pw, re, im, part, summary);
    // 4) fused spectral+skip GEMM, A-in-regs + B-LDS (unclamped VGPR) -> yact
    gemm2_areg<<<dim3(24, 64), dim3(256), 0, stream>>>(summary, xb, WsCat, WiCat, yact);
    // 5) out = yact @ W_out  (MFMA)
    gemm_bf16_mfma<<<dim3(6, 64), blk, 0, stream>>>(yact, WoT, out, 2304, 768, 768);
}

// Round 8
// 399.281 us; speedup vs baseline: 1.4946x; 1.4946x over previous
//
#include <hip/hip_runtime.h>
#include <hip/hip_bf16.h>

// Problem constants (B,L,D)=(4,2048,768), K=12, M=1, CK=4, H=64
#define B_       4
#define L_       2048
#define D_       768
#define K_       12
#define H_       64
#define CK_      4
#define DIM_MEM_ 768
#define DMK      780        // DIM_MEM + K
#define NT       (B_*L_)    // 8192 tokens
#define NSUM     1536       // 2*K*H  (summary width)
#define NACT     2304       // K*192  (y_act width)
#define NCHUNK   16
#define CHLEN    (L_/NCHUNK)  // 128
#define PSTRIDE  132

typedef __attribute__((ext_vector_type(8))) short          bf16x8;
typedef __attribute__((ext_vector_type(8))) unsigned short u16x8;
typedef __attribute__((ext_vector_type(4))) float          f32x4;

__device__ __forceinline__ ushort f2bf(float v) {
    __hip_bfloat16 h = __float2bfloat16(v);
    return *reinterpret_cast<ushort*>(&h);
}
// fast tanh via hw exp; safe for any x
__device__ __forceinline__ float tanh_fast(float x) {
    float t = __expf(-2.f * fabsf(x));
    float r = (1.f - t) / (1.f + t);
    return copysignf(r, x);
}

// ---------------------------------------------------------------------------
// Merged prep: transpose-cast jobs (32x32 LDS tiles) + x->bf16 cast.
// remap==1: interleaved val/gate layout for the fused spectral GEMM:
//   virtual col vc: grp=vc>>5, which=(vc>>4)&1, nn=grp*16+(vc&15)
//   orig col = colbase + (nn/192)*384 + which*192 + (nn%192)
// ---------------------------------------------------------------------------
struct PrepJobs {
    const float* W[6];
    ushort*      out[6];
    int ldw[6], Kd[6], colbase[6], remap[6], ntx[6];
    int start[7];
    const float* cast_in;
    ushort*      cast_out;
    int n4;
};

__global__ __launch_bounds__(256)
void prep_all(PrepJobs J)
{
    int blk = blockIdx.x;
    if (blk >= J.start[6]) {                       // cast job
        int i = (blk - J.start[6]) * 256 + threadIdx.x;
        if (i < J.n4) {
            float4 v = reinterpret_cast<const float4*>(J.cast_in)[i];
            ushort4 o;
            o.x = f2bf(v.x); o.y = f2bf(v.y); o.z = f2bf(v.z); o.w = f2bf(v.w);
            reinterpret_cast<ushort4*>(J.cast_out)[i] = o;
        }
        return;
    }
    int j = 0;
    while (blk >= J.start[j + 1]) ++j;
    int rel = blk - J.start[j];
    int ntx = J.ntx[j];
    int n0 = (rel % ntx) * 32, k0 = (rel / ntx) * 32;
    const float* W = J.W[j];
    int ldw = J.ldw[j], Kd = J.Kd[j], colbase = J.colbase[j], remap = J.remap[j];
    ushort* out = J.out[j];

    __shared__ float tile[32][33];
    int tx = threadIdx.x & 31, ty = threadIdx.x >> 5;
    int n = n0 + tx;
    int c;
    if (remap) {
        int grp = n >> 5, which = (n >> 4) & 1, nn = (grp << 4) + (n & 15);
        c = colbase + (nn / 192) * 384 + which * 192 + (nn % 192);
    } else {
        c = colbase + n;
    }
    #pragma unroll
    for (int r = 0; r < 4; ++r)
        tile[ty + r*8][tx] = W[(size_t)(k0 + ty + r*8) * ldw + c];
    __syncthreads();
    #pragma unroll
    for (int r = 0; r < 4; ++r)
        out[(size_t)(n0 + ty + r*8) * Kd + k0 + tx] = f2bf(tile[tx][ty + r*8]);
}

// ---------------------------------------------------------------------------
// bf16 MFMA GEMM: C[M,N] fp32 = A[M,K] * BT[Nr,K]^T, write guard col<N.
// 128x128 tile, BK=64, 4 waves each 64x64. PROVEN sync discipline only.
// ---------------------------------------------------------------------------
__global__ __launch_bounds__(256)
void gemm_bf16_mfma(const ushort* __restrict__ A, const ushort* __restrict__ BT,
                    float* __restrict__ C, int Kd, int N, int ldc)
{
    __shared__ ushort As[128*64];   // 16 KB
    __shared__ ushort Bs[128*64];   // 16 KB
    int tid = threadIdx.x, lane = tid & 63;
    int lr = lane & 15, quad = lane >> 4;
    int wave = tid >> 6;
    int wr = (wave >> 1) * 64, wc = (wave & 1) * 64;
    int m0 = blockIdx.y * 128, n0 = blockIdx.x * 128;

    f32x4 acc[4][4] = {};

    int srow = tid >> 3;                       // 0..31
    int tc   = tid & 7;                        // logical k-chunk (8B*2=16B)
    const ushort* gA = A  + (size_t)(m0 + srow) * Kd + tc * 8;
    const ushort* gB = BT + (size_t)(n0 + srow) * Kd + tc * 8;
    int woff = srow * 64 + ((tc ^ (srow & 7)) * 8);
    int rx = lr & 7;

    for (int k0 = 0; k0 < Kd; k0 += 64) {
        u16x8 a[4], b[4];
        #pragma unroll
        for (int p = 0; p < 4; ++p) {
            a[p] = *reinterpret_cast<const u16x8*>(gA + (size_t)(32*p) * Kd);
            b[p] = *reinterpret_cast<const u16x8*>(gB + (size_t)(32*p) * Kd);
        }
        gA += 64; gB += 64;
        __syncthreads();               // prev iteration's LDS reads complete
        #pragma unroll
        for (int p = 0; p < 4; ++p) {
            *reinterpret_cast<u16x8*>(As + woff + p*2048) = a[p];
            *reinterpret_cast<u16x8*>(Bs + woff + p*2048) = b[p];
        }
        __syncthreads();               // staging visible to all waves
        #pragma unroll
        for (int ks = 0; ks < 2; ++ks) {
            bf16x8 af[4], bf[4];
            #pragma unroll
            for (int i = 0; i < 4; ++i) {
                int ca = ((ks*4 + quad) ^ rx) * 8;
                af[i] = *reinterpret_cast<const bf16x8*>(As + (wr + i*16 + lr) * 64 + ca);
                bf[i] = *reinterpret_cast<const bf16x8*>(Bs + (wc + i*16 + lr) * 64 + ca);
            }
            #pragma unroll
            for (int i = 0; i < 4; ++i)
                #pragma unroll
                for (int j = 0; j < 4; ++j)
                    acc[i][j] = __builtin_amdgcn_mfma_f32_16x16x32_bf16(
                                    af[i], bf[j], acc[i][j], 0, 0, 0);
        }
    }

    #pragma unroll
    for (int i = 0; i < 4; ++i)
        #pragma unroll
        for (int j = 0; j < 4; ++j)
            #pragma unroll
            for (int r = 0; r < 4; ++r) {
                int row = m0 + wr + i*16 + quad*4 + r;      // m89-verified C/D map
                int col = n0 + wc + j*16 + lr;
                if (col < N)
                    C[(size_t)row * ldc + col] = acc[i][j][r];
            }
}

// ---------------------------------------------------------------------------
// Fused spectral+skip GEMM, single-phase pipelined + 2 blocks/CU (r3-proven:
// 147us, MfmaUtil 55%, VGPR 100). A+B staged via global_load_lds with XOR
// swizzle; one vmcnt(0)+barrier per K-tile; compiler-scheduled lgkm waits.
// ---------------------------------------------------------------------------
#define G2NKT 36   // 24 k-tiles of summary (K=1536) + 12 of x (K=768)

#define GLOAD16(gp, dp) __builtin_amdgcn_global_load_lds( \
    (__attribute__((address_space(1))) const void*)(gp),  \
    (__attribute__((address_space(3))) void*)(dp), 16, 0, 0)

__device__ __forceinline__ void g2_stageA(ushort* lds_, int kt,
                                          const ushort* pAs, const ushort* pAx,
                                          int wave, int part)
{
    int ktc = kt > (G2NKT-1) ? (G2NKT-1) : kt;   // clamp src; dest parity uses kt
    const ushort* g; size_t kd;
    if (ktc < 24) { g = pAs + ktc*64;      kd = 1536; }
    else          { g = pAx + (ktc-24)*64; kd = 768;  }
    g += (size_t)(part * 64) * kd;               // rows part*64 .. part*64+63
    ushort* d = lds_ + (kt & 1) * 8192 + part * 4096 + wave * 512;
    GLOAD16(g,           d);
    GLOAD16(g + 32*kd,   d + 2048);
}

__device__ __forceinline__ void g2_stageB(ushort* lds_, int kt,
                                          const ushort* pBs, const ushort* pBx,
                                          int wave)
{
    int ktc = kt > (G2NKT-1) ? (G2NKT-1) : kt;
    const ushort* g; size_t kd;
    if (ktc < 24) { g = pBs + ktc*64;      kd = 1536; }
    else          { g = pBx + (ktc-24)*64; kd = 768;  }
    ushort* d = lds_ + 16384 + (kt & 1) * 12288 + wave * 512;
    #pragma unroll
    for (int s = 0; s < 6; ++s)
        GLOAD16(g + (size_t)(32*s)*kd, d + 2048*s);
}

__global__ __launch_bounds__(256, 2)
void gemm2_1ph(const ushort* __restrict__ Sm, const ushort* __restrict__ Xb,
               const ushort* __restrict__ WsC, const ushort* __restrict__ WiC,
               ushort* __restrict__ yact)
{
    // LDS (ushort units): A bufs @0 and @8192 (128x64 each);
    //                     B bufs @16384 and @28672 (192x64 each). 80 KiB.
    __shared__ ushort lds[40960];
    const int tid  = threadIdx.x;
    const int lane = tid & 63, wave = tid >> 6;      // wave 0..3
    const int lr = lane & 15, quad = lane >> 4, rx = lr & 7;
    const int wr = (wave >> 1) * 64;     // 0,64
    const int wc = (wave & 1) * 96;      // 0,96
    const int m0 = blockIdx.y * 128, n0 = blockIdx.x * 192;

    // staging source pointers (pre-swizzled chunk): LDS[row][c] holds global
    // chunk c^(row&7); reader XORs the same way.
    const int sr = tid >> 3;             // 0..31
    const int sc = (tid & 7) ^ (sr & 7);
    const ushort* pAs = Sm  + (size_t)(m0 + sr) * 1536 + sc * 8;
    const ushort* pAx = Xb  + (size_t)(m0 + sr) * 768  + sc * 8;
    const ushort* pBs = WsC + (size_t)(n0 + sr) * 1536 + sc * 8;
    const ushort* pBx = WiC + (size_t)(n0 + sr) * 768  + sc * 8;

    f32x4 acc[4][6] = {};
    const int ca0 = (quad ^ rx) * 8;
    const int ca1 = ((4 + quad) ^ rx) * 8;

    // prologue: A(0) + B(0) = 10 loads; drain, barrier.
    g2_stageA(lds, 0, pAs, pAx, wave, 0);
    g2_stageA(lds, 0, pAs, pAx, wave, 1);
    g2_stageB(lds, 0, pBs, pBx, wave);
    asm volatile("s_waitcnt vmcnt(0)" ::: "memory");
    __builtin_amdgcn_s_barrier();

    #pragma unroll 1
    for (int g = 0; g < G2NKT; ++g) {
        const ushort* Ab = lds + (g & 1) * 8192;
        const ushort* Bb = lds + 16384 + (g & 1) * 12288;

        // issue next-tile stages first (max latency cover; opposite buffer)
        g2_stageA(lds, g + 1, pAs, pAx, wave, 0);
        g2_stageA(lds, g + 1, pAs, pAx, wave, 1);
        g2_stageB(lds, g + 1, pBs, pBx, wave);

        // fragments: compiler schedules ds_reads + fine-grained lgkm waits
        bf16x8 af[4][2], bfr[6][2];
        #pragma unroll
        for (int i = 0; i < 4; ++i) {
            const ushort* p = Ab + (wr + i*16 + lr) * 64;
            af[i][0] = *reinterpret_cast<const bf16x8*>(p + ca0);
            af[i][1] = *reinterpret_cast<const bf16x8*>(p + ca1);
        }
        #pragma unroll
        for (int j = 0; j < 6; ++j) {
            const ushort* p = Bb + (wc + j*16 + lr) * 64;
            bfr[j][0] = *reinterpret_cast<const bf16x8*>(p + ca0);
            bfr[j][1] = *reinterpret_cast<const bf16x8*>(p + ca1);
        }
        __builtin_amdgcn_s_setprio(1);
        #pragma unroll
        for (int ks = 0; ks < 2; ++ks)
            #pragma unroll
            for (int i = 0; i < 4; ++i)
                #pragma unroll
                for (int j = 0; j < 6; ++j)
                    acc[i][j] = __builtin_amdgcn_mfma_f32_16x16x32_bf16(
                                    af[i][ks], bfr[j][ks], acc[i][j], 0, 0, 0);
        __builtin_amdgcn_s_setprio(0);

        // drain next-tile stage (covered by the 48-MFMA burst), flip buffers
        asm volatile("s_waitcnt vmcnt(0)" ::: "memory");
        __builtin_amdgcn_s_barrier();
    }

    // epilogue: lane-local (val,gate) pairs -> gated SiLU -> bf16
    const int vg0 = (n0 + wc) >> 5;
    #pragma unroll
    for (int i = 0; i < 4; ++i)
        #pragma unroll
        for (int p = 0; p < 3; ++p)
            #pragma unroll
            for (int r = 0; r < 4; ++r) {
                int row = m0 + wr + i*16 + quad*4 + r;      // m89-verified C/D map
                int col = (vg0 + p)*16 + lr;
                float v  = acc[i][2*p][r];
                float gt = acc[i][2*p + 1][r];
                float y = v * (gt / (1.f + __expf(-gt)));
                yact[(size_t)row * NACT + col] = f2bf(y);
            }
}

// ---------------------------------------------------------------------------
// Fused token+scan pass 1: one block per (b,k,chunk), 128 thr = 2 waves.
// Wave tt owns tokens [chunk*128 + tt*64, +64), lane = h. Computes
// conv(CK=4)+SiLU+RMSNorm(H=64 shfl)+phase, writes re/im in chunk-local
// coalesced layout [blk][tok][h], pw in [bk][l], and the chunk partial sums
// (replacing scan_sums). zmem is read ONCE (rolling-scalar conv window,
// 8-token batched loads) vs 4x in the old per-token kernel.
// Same FP expressions/order per element as the old token_kernel.
// ---------------------------------------------------------------------------
__global__ __launch_bounds__(128)
void token_scan1(const float* __restrict__ zmem, const float* __restrict__ conv_w,
                 const float* __restrict__ rms_scale, const float* __restrict__ theta_raw,
                 const float* __restrict__ dslopes, const float* __restrict__ sscale,
                 const float* __restrict__ tscale,
                 float* __restrict__ reN, float* __restrict__ imN,
                 float* __restrict__ pwN, float* __restrict__ part)
{
    int blk = blockIdx.x;            // = bk*16 + chunk
    int chunk = blk & (NCHUNK - 1);
    int bk = blk >> 4;
    int k = bk % K_;
    int b = bk / K_;
    int tid = threadIdx.x;
    int h = tid & 63;
    int tt = tid >> 6;               // wave -> token sub-range
    int l0 = chunk * CHLEN + tt * 64;

    int c  = k*H_ + h;
    int cs = DIM_MEM_ + k;

    // hoisted per-thread constants
    float cw0 = conv_w[0*DMK + c], cw1 = conv_w[1*DMK + c];
    float cw2 = conv_w[2*DMK + c], cw3 = conv_w[3*DMK + c];
    float cs0 = conv_w[0*DMK + cs], cs1 = conv_w[1*DMK + cs];
    float cs2 = conv_w[2*DMK + cs], cs3 = conv_w[3*DMK + cs];
    float rs  = rms_scale[h];
    float th  = 0.001f + 2.999f * (1.f / (1.f + __expf(-theta_raw[c])));
    float ts  = tscale[k];
    float scl = sscale[k];
    float slope = log1pf(expf(dslopes[k]));

    const float* zb = zmem + (size_t)(b*L_) * DMK;

    // rolling window carry: z3=row(l-3), z2=row(l-2), z1=row(l-1)
    float z3=0.f, z2=0.f, z1=0.f, s3=0.f, s2=0.f, s1=0.f;
    {
        int ll = l0 - 3;
        if (ll >= 0)     { z3 = zb[(size_t)ll*DMK + c];     s3 = zb[(size_t)ll*DMK + cs]; }
        if (ll + 1 >= 0) { z2 = zb[(size_t)(ll+1)*DMK + c]; s2 = zb[(size_t)(ll+1)*DMK + cs]; }
        if (ll + 2 >= 0) { z1 = zb[(size_t)(ll+2)*DMK + c]; s1 = zb[(size_t)(ll+2)*DMK + cs]; }
    }

    float sre = 0.f, sim = 0.f, spw = 0.f;
    size_t obase = (size_t)blk * (CHLEN*H_) + (size_t)(tt*64)*H_ + h;

    for (int i0 = 0; i0 < 64; i0 += 8) {
        float zl[8], sl[8];
        #pragma unroll
        for (int j = 0; j < 8; ++j) {
            int l = l0 + i0 + j;
            zl[j] = zb[(size_t)l*DMK + c];
            sl[j] = zb[(size_t)l*DMK + cs];
        }
        #pragma unroll
        for (int j = 0; j < 8; ++j) {
            int l = l0 + i0 + j;
            float a3 = zl[j], b3 = sl[j];
            float acc  = cw0*z3 + cw1*z2 + cw2*z1 + cw3*a3;
            float acc2 = cs0*s3 + cs1*s2 + cs2*s1 + cs3*b3;
            z3 = z2; z2 = z1; z1 = a3;       // roll the windows (pure scalars)
            s3 = s2; s2 = s1; s1 = b3;

            float kv = acc / (1.f + __expf(-acc));          // silu (hw exp)
            float ss = kv * kv;
            #pragma unroll
            for (int off = 32; off > 0; off >>= 1)
                ss += __shfl_xor(ss, off, 64);
            float kn  = kv * rsqrtf(ss * (1.f/64.f) + 1e-6f) * rs;
            float phi = tanh_fast(kn * ts) * th;

            float s  = acc2 / (1.f + expf(-acc2));          // match original expf
            float lp = fminf(10.f, fmaxf(-10.f, scl * s));
            float pwv = expf(lp - slope * (float)(L_ - 1 - l));

            float kvw = kn * pwv;
            float rev = kvw * __cosf(phi);
            float imv = kvw * __sinf(phi);
            reN[obase + (size_t)(i0 + j)*H_] = rev;
            imN[obase + (size_t)(i0 + j)*H_] = imv;
            sre += rev; sim += imv; spw += pwv;
            if (h == 0) pwN[(size_t)bk * L_ + l] = pwv;
        }
    }

    // cross-wave combine -> chunk partials (same layout as old scan_sums)
    __shared__ float red[2][64], imd[2][64], pwd[2];
    red[tt][h] = sre; imd[tt][h] = sim;
    if (h == 0) pwd[tt] = spw;
    __syncthreads();
    size_t pb = (size_t)blk * PSTRIDE;
    if (tid < 64) part[pb + tid] = red[0][tid] + red[1][tid];
    else          part[pb + tid] = imd[0][tid - 64] + imd[1][tid - 64];
    if (tid == 0) part[pb + 128] = pwd[0] + pwd[1];
}

// ---------------------------------------------------------------------------
// Scan pass 2 on the chunk-local layout: prefix from partials, emit bf16
// summary. Identical accumulation order to the old scan_final.
// ---------------------------------------------------------------------------
__global__ __launch_bounds__(128)
void scan_final2(const float* __restrict__ pwN, const float* __restrict__ reN,
                 const float* __restrict__ imN, const float* __restrict__ part,
                 ushort* __restrict__ summary)
{
    int blk = blockIdx.x;
    int chunk = blk & (NCHUNK - 1);
    int bk = blk >> 4;
    int k = bk % K_;
    int b = bk / K_;
    int tid = threadIdx.x;
    int h = tid & 63;
    int pi = tid >> 6;
    const float* __restrict__ src = pi ? imN : reN;
    int l0 = chunk * CHLEN;

    float acc = 0.f, dacc = 0.f;
    size_t pb0 = (size_t)(bk * NCHUNK) * PSTRIDE;
    for (int cn = 0; cn < chunk; ++cn) {
        acc  += part[pb0 + (size_t)cn*PSTRIDE + tid];
        dacc += part[pb0 + (size_t)cn*PSTRIDE + 128];
    }

    size_t base  = (size_t)blk * (CHLEN*H_) + h;
    size_t dbase = (size_t)bk * L_ + l0;
    int outch = 2*(k*H_ + h) + pi;
    for (int i0 = 0; i0 < CHLEN; i0 += 8) {
        float v[8], d[8];
        #pragma unroll
        for (int j = 0; j < 8; ++j) {
            v[j] = src[base + (size_t)(i0 + j)*H_];
            d[j] = pwN[dbase + i0 + j];
        }
        #pragma unroll
        for (int j = 0; j < 8; ++j) {
            acc += v[j]; dacc += d[j];
            float inv = 1.f / fmaxf(dacc, 1e-4f);
            summary[((size_t)(b*L_ + l0 + i0 + j))*NSUM + outch] = f2bf(acc * inv);
        }
    }
}

// ---------------------------------------------------------------------------
extern "C" void kernel_launch(void* const* d_in, const int* in_sizes, int n_in,
                              void* d_out, int out_size, void* d_ws, size_t ws_size,
                              hipStream_t stream)
{
    const float* x         = (const float*)d_in[0];
    const float* W_in      = (const float*)d_in[1];
    const float* conv_w    = (const float*)d_in[2];
    const float* rms_scale = (const float*)d_in[3];
    const float* theta_raw = (const float*)d_in[4];
    const float* dslopes   = (const float*)d_in[5];
    const float* sscale    = (const float*)d_in[6];
    const float* tscale    = (const float*)d_in[7];
    const float* W_sw      = (const float*)d_in[8];
    const float* W_out     = (const float*)d_in[9];
    float* out = (float*)d_out;
    char* ws   = (char*)d_ws;

    // Workspace (byte offsets, all 256-aligned). Peak ~115.4 MB (< proven 127).
    float*  zmem    = (float*) (ws + 0);           // NT*780 f32   = 25,559,040 B
    ushort* summary = (ushort*)(ws + 0);           // alias (zmem dead): 25,165,824 B
    float*  pw      = (float*) (ws + 25559040);    //   393,216 B  [bk][l]
    float*  re      = (float*) (ws + 25952256);    // 25,165,824 B [blk][tok][h]
    float*  im      = (float*) (ws + 51118080);    // 25,165,824 B
    ushort* yact    = (ushort*)(ws + 25952256);    // alias re+im (dead): 37,748,736 B
    float*  part    = (float*) (ws + 76283904);    //   405,504 B
    ushort* xb      = (ushort*)(ws + 76689408);    // 12,582,912 B
    ushort* WiCat   = (ushort*)(ws + 89272320);    //  7,077,888 B  [4608][768]  val/gate interleaved
    ushort* WsCat   = (ushort*)(ws + 96350208);    // 14,155,776 B  [4608][1536] val/gate interleaved
    ushort* WoT     = (ushort*)(ws + 110505984);   //  3,538,944 B  [768][2304]
    ushort* WimT    = (ushort*)(ws + 114044928);   //  1,376,256 B  [896][768] (pad)

    // ---- merged prep job table ----
    PrepJobs J{};
    J.W[0]=W_in;  J.out[0]=WiCat; J.ldw[0]=5388; J.Kd[0]=768;  J.colbase[0]=780; J.remap[0]=1; J.ntx[0]=144;
    J.W[1]=W_sw;  J.out[1]=WsCat; J.ldw[1]=4608; J.Kd[1]=1536; J.colbase[1]=0;   J.remap[1]=1; J.ntx[1]=144;
    J.W[2]=W_out; J.out[2]=WoT;   J.ldw[2]=768;  J.Kd[2]=2304; J.colbase[2]=0;   J.remap[2]=0; J.ntx[2]=24;
    J.W[3]=W_in;  J.out[3]=WimT;  J.ldw[3]=5388; J.Kd[3]=768;  J.colbase[3]=0;   J.remap[3]=0; J.ntx[3]=28;
    int tiles[4] = {144*24, 144*48, 24*72, 28*24};
    J.start[0] = 0;
    for (int j = 0; j < 4; ++j) J.start[j+1] = J.start[j] + tiles[j];
    J.start[5] = J.start[4];
    J.start[6] = J.start[4];
    J.cast_in = x; J.cast_out = xb; J.n4 = NT*D_/4;
    int nblk = J.start[6] + (J.n4 + 255)/256;

    dim3 blk(256);
    // 0) all preps in one launch
    prep_all<<<dim3(nblk), blk, 0, stream>>>(J);
    // 1) z_mem = x @ W_in[:, :780]  (bf16 MFMA, col-guarded at 780)
    gemm_bf16_mfma<<<dim3(7, 64), blk, 0, stream>>>(xb, WimT, zmem, 768, 780, 780);
    // 2) fused conv+silu+rmsnorm+phase + chunk partial sums (1x zmem read)
    token_scan1<<<dim3(B_*K_*NCHUNK), dim3(128), 0, stream>>>(
        zmem, conv_w, rms_scale, theta_raw, dslopes, sscale, tscale,
        re, im, pw, part);
    // 3) prefix + emit summary (bf16)
    scan_final2<<<dim3(B_*K_*NCHUNK), dim3(128), 0, stream>>>(pw, re, im, part, summary);
    // 4) fused spectral+skip single-phase pipelined GEMM, 2 blocks/CU -> yact
    gemm2_1ph<<<dim3(24, 64), dim3(256), 0, stream>>>(summary, xb, WsCat, WiCat, yact);
    // 5) out = yact @ W_out  (MFMA)
    gemm_bf16_mfma<<<dim3(6, 64), blk, 0, stream>>>(yact, WoT, out, 2304, 768, 768);
}

// Round 9
// 394.554 us; speedup vs baseline: 1.5125x; 1.0120x over previous
//
#include <hip/hip_runtime.h>
#include <hip/hip_bf16.h>

// Problem constants (B,L,D)=(4,2048,768), K=12, M=1, CK=4, H=64
#define B_       4
#define L_       2048
#define D_       768
#define K_       12
#define H_       64
#define CK_      4
#define DIM_MEM_ 768
#define DMK      780        // DIM_MEM + K
#define NT       (B_*L_)    // 8192 tokens
#define NSUM     1536       // 2*K*H  (summary width)
#define NACT     2304       // K*192  (y_act width)
#define NCHUNK   16
#define CHLEN    (L_/NCHUNK)  // 128
#define PSTRIDE  132

typedef __attribute__((ext_vector_type(8))) short          bf16x8;
typedef __attribute__((ext_vector_type(8))) unsigned short u16x8;
typedef __attribute__((ext_vector_type(4))) float          f32x4;

__device__ __forceinline__ ushort f2bf(float v) {
    __hip_bfloat16 h = __float2bfloat16(v);
    return *reinterpret_cast<ushort*>(&h);
}
// fast tanh via hw exp; safe for any x
__device__ __forceinline__ float tanh_fast(float x) {
    float t = __expf(-2.f * fabsf(x));
    float r = (1.f - t) / (1.f + t);
    return copysignf(r, x);
}

// ---------------------------------------------------------------------------
// Merged prep: transpose-cast jobs (32x32 LDS tiles) + x->bf16 cast.
// remap==1: interleaved val/gate layout for the fused spectral GEMM:
//   virtual col vc: grp=vc>>5, which=(vc>>4)&1, nn=grp*16+(vc&15)
//   orig col = colbase + (nn/192)*384 + which*192 + (nn%192)
// ---------------------------------------------------------------------------
struct PrepJobs {
    const float* W[6];
    ushort*      out[6];
    int ldw[6], Kd[6], colbase[6], remap[6], ntx[6];
    int start[7];
    const float* cast_in;
    ushort*      cast_out;
    int n4;
};

__global__ __launch_bounds__(256)
void prep_all(PrepJobs J)
{
    int blk = blockIdx.x;
    if (blk >= J.start[6]) {                       // cast job
        int i = (blk - J.start[6]) * 256 + threadIdx.x;
        if (i < J.n4) {
            float4 v = reinterpret_cast<const float4*>(J.cast_in)[i];
            ushort4 o;
            o.x = f2bf(v.x); o.y = f2bf(v.y); o.z = f2bf(v.z); o.w = f2bf(v.w);
            reinterpret_cast<ushort4*>(J.cast_out)[i] = o;
        }
        return;
    }
    int j = 0;
    while (blk >= J.start[j + 1]) ++j;
    int rel = blk - J.start[j];
    int ntx = J.ntx[j];
    int n0 = (rel % ntx) * 32, k0 = (rel / ntx) * 32;
    const float* W = J.W[j];
    int ldw = J.ldw[j], Kd = J.Kd[j], colbase = J.colbase[j], remap = J.remap[j];
    ushort* out = J.out[j];

    __shared__ float tile[32][33];
    int tx = threadIdx.x & 31, ty = threadIdx.x >> 5;
    int n = n0 + tx;
    int c;
    if (remap) {
        int grp = n >> 5, which = (n >> 4) & 1, nn = (grp << 4) + (n & 15);
        c = colbase + (nn / 192) * 384 + which * 192 + (nn % 192);
    } else {
        c = colbase + n;
    }
    #pragma unroll
    for (int r = 0; r < 4; ++r)
        tile[ty + r*8][tx] = W[(size_t)(k0 + ty + r*8) * ldw + c];
    __syncthreads();
    #pragma unroll
    for (int r = 0; r < 4; ++r)
        out[(size_t)(n0 + ty + r*8) * Kd + k0 + tx] = f2bf(tile[tx][ty + r*8]);
}

// ---------------------------------------------------------------------------
// global_load_lds staging macro (width 16)
// ---------------------------------------------------------------------------
#define GLOAD16(gp, dp) __builtin_amdgcn_global_load_lds( \
    (__attribute__((address_space(1))) const void*)(gp),  \
    (__attribute__((address_space(3))) void*)(dp), 16, 0, 0)

// ---------------------------------------------------------------------------
// bf16 MFMA GEMM, 1-phase pipelined + 2 blocks/CU (ported from the proven
// gemm2_1ph structure): C[M,N] f32 = A[M,K] * BT[N,K]^T, col<N write guard.
// 128x128 tile, BK=64, 4 waves (2x2, 64x64/wave). A+B staged via
// global_load_lds w16, pre-swizzled global source chunk c^(row&7) + same XOR
// on the LDS read side. Per K-tile: issue next-tile stages (8 loads, opposite
// buffer) -> frag ds_reads (compiler-scheduled lgkm waits) -> 32 MFMA under
// setprio -> one vmcnt(0)+barrier. LDS 64 KB -> 2 blocks/CU (TLP overlap).
// WAR safety: stage targets buf[(g+1)&1], whose reads all happened in
// iteration g-1, ordered by g-1's end barrier.
// ---------------------------------------------------------------------------
__device__ __forceinline__ void g13_stage(ushort* dst, const ushort* src, int kd)
{
    #pragma unroll
    for (int s = 0; s < 4; ++s)
        GLOAD16(src + (size_t)(32*s)*kd, dst + 2048*s);
}

__global__ __launch_bounds__(256, 2)
void gemm13_1ph(const ushort* __restrict__ A, const ushort* __restrict__ BT,
                float* __restrict__ C, int Kd, int N, int ldc)
{
    // LDS (ushort units): A bufs @0,@8192 (128x64 each, 16 KB);
    //                     B bufs @16384,@24576. Total 64 KB.
    __shared__ ushort lds[32768];
    const int tid  = threadIdx.x;
    const int lane = tid & 63, wave = tid >> 6;
    const int lr = lane & 15, quad = lane >> 4, rx = lr & 7;
    const int wr = (wave >> 1) * 64, wc = (wave & 1) * 64;
    const int m0 = blockIdx.y * 128, n0 = blockIdx.x * 128;
    const int NKT = Kd >> 6;

    // staging source pointers (pre-swizzled chunk)
    const int sr = tid >> 3;             // 0..31
    const int sc = (tid & 7) ^ (sr & 7);
    const ushort* pA = A  + (size_t)(m0 + sr) * Kd + sc * 8;
    const ushort* pB = BT + (size_t)(n0 + sr) * Kd + sc * 8;

    f32x4 acc[4][4] = {};
    const int ca0 = (quad ^ rx) * 8;
    const int ca1 = ((4 + quad) ^ rx) * 8;

    // prologue: stage tile 0 into buf 0; drain, barrier.
    g13_stage(lds + wave*512,         pA, Kd);
    g13_stage(lds + 16384 + wave*512, pB, Kd);
    asm volatile("s_waitcnt vmcnt(0)" ::: "memory");
    __builtin_amdgcn_s_barrier();

    #pragma unroll 1
    for (int g = 0; g < NKT; ++g) {
        const ushort* Ab = lds + (g & 1) * 8192;
        const ushort* Bb = lds + 16384 + (g & 1) * 8192;

        // issue next-tile stages first (opposite buffer; clamp src at last)
        int nk = (g + 1 < NKT) ? g + 1 : NKT - 1;
        g13_stage(lds + ((g + 1) & 1) * 8192 + wave*512,         pA + nk*64, Kd);
        g13_stage(lds + 16384 + ((g + 1) & 1) * 8192 + wave*512, pB + nk*64, Kd);

        bf16x8 af[4][2], bf[4][2];
        #pragma unroll
        for (int i = 0; i < 4; ++i) {
            const ushort* p = Ab + (wr + i*16 + lr) * 64;
            af[i][0] = *reinterpret_cast<const bf16x8*>(p + ca0);
            af[i][1] = *reinterpret_cast<const bf16x8*>(p + ca1);
        }
        #pragma unroll
        for (int j = 0; j < 4; ++j) {
            const ushort* p = Bb + (wc + j*16 + lr) * 64;
            bf[j][0] = *reinterpret_cast<const bf16x8*>(p + ca0);
            bf[j][1] = *reinterpret_cast<const bf16x8*>(p + ca1);
        }
        __builtin_amdgcn_s_setprio(1);
        #pragma unroll
        for (int ks = 0; ks < 2; ++ks)
            #pragma unroll
            for (int i = 0; i < 4; ++i)
                #pragma unroll
                for (int j = 0; j < 4; ++j)
                    acc[i][j] = __builtin_amdgcn_mfma_f32_16x16x32_bf16(
                                    af[i][ks], bf[j][ks], acc[i][j], 0, 0, 0);
        __builtin_amdgcn_s_setprio(0);

        asm volatile("s_waitcnt vmcnt(0)" ::: "memory");
        __builtin_amdgcn_s_barrier();
    }

    #pragma unroll
    for (int i = 0; i < 4; ++i)
        #pragma unroll
        for (int j = 0; j < 4; ++j)
            #pragma unroll
            for (int r = 0; r < 4; ++r) {
                int row = m0 + wr + i*16 + quad*4 + r;      // m89-verified C/D map
                int col = n0 + wc + j*16 + lr;
                if (col < N)
                    C[(size_t)row * ldc + col] = acc[i][j][r];
            }
}

// ---------------------------------------------------------------------------
// Fused spectral+skip GEMM, single-phase pipelined + 2 blocks/CU (r3/r8
// proven: 146us, MfmaUtil 56%, VGPR 100).
// ---------------------------------------------------------------------------
#define G2NKT 36   // 24 k-tiles of summary (K=1536) + 12 of x (K=768)

__device__ __forceinline__ void g2_stageA(ushort* lds_, int kt,
                                          const ushort* pAs, const ushort* pAx,
                                          int wave, int part)
{
    int ktc = kt > (G2NKT-1) ? (G2NKT-1) : kt;   // clamp src; dest parity uses kt
    const ushort* g; size_t kd;
    if (ktc < 24) { g = pAs + ktc*64;      kd = 1536; }
    else          { g = pAx + (ktc-24)*64; kd = 768;  }
    g += (size_t)(part * 64) * kd;               // rows part*64 .. part*64+63
    ushort* d = lds_ + (kt & 1) * 8192 + part * 4096 + wave * 512;
    GLOAD16(g,           d);
    GLOAD16(g + 32*kd,   d + 2048);
}

__device__ __forceinline__ void g2_stageB(ushort* lds_, int kt,
                                          const ushort* pBs, const ushort* pBx,
                                          int wave)
{
    int ktc = kt > (G2NKT-1) ? (G2NKT-1) : kt;
    const ushort* g; size_t kd;
    if (ktc < 24) { g = pBs + ktc*64;      kd = 1536; }
    else          { g = pBx + (ktc-24)*64; kd = 768;  }
    ushort* d = lds_ + 16384 + (kt & 1) * 12288 + wave * 512;
    #pragma unroll
    for (int s = 0; s < 6; ++s)
        GLOAD16(g + (size_t)(32*s)*kd, d + 2048*s);
}

__global__ __launch_bounds__(256, 2)
void gemm2_1ph(const ushort* __restrict__ Sm, const ushort* __restrict__ Xb,
               const ushort* __restrict__ WsC, const ushort* __restrict__ WiC,
               ushort* __restrict__ yact)
{
    // LDS (ushort units): A bufs @0 and @8192 (128x64 each);
    //                     B bufs @16384 and @28672 (192x64 each). 80 KiB.
    __shared__ ushort lds[40960];
    const int tid  = threadIdx.x;
    const int lane = tid & 63, wave = tid >> 6;      // wave 0..3
    const int lr = lane & 15, quad = lane >> 4, rx = lr & 7;
    const int wr = (wave >> 1) * 64;     // 0,64
    const int wc = (wave & 1) * 96;      // 0,96
    const int m0 = blockIdx.y * 128, n0 = blockIdx.x * 192;

    // staging source pointers (pre-swizzled chunk): LDS[row][c] holds global
    // chunk c^(row&7); reader XORs the same way.
    const int sr = tid >> 3;             // 0..31
    const int sc = (tid & 7) ^ (sr & 7);
    const ushort* pAs = Sm  + (size_t)(m0 + sr) * 1536 + sc * 8;
    const ushort* pAx = Xb  + (size_t)(m0 + sr) * 768  + sc * 8;
    const ushort* pBs = WsC + (size_t)(n0 + sr) * 1536 + sc * 8;
    const ushort* pBx = WiC + (size_t)(n0 + sr) * 768  + sc * 8;

    f32x4 acc[4][6] = {};
    const int ca0 = (quad ^ rx) * 8;
    const int ca1 = ((4 + quad) ^ rx) * 8;

    // prologue: A(0) + B(0) = 10 loads; drain, barrier.
    g2_stageA(lds, 0, pAs, pAx, wave, 0);
    g2_stageA(lds, 0, pAs, pAx, wave, 1);
    g2_stageB(lds, 0, pBs, pBx, wave);
    asm volatile("s_waitcnt vmcnt(0)" ::: "memory");
    __builtin_amdgcn_s_barrier();

    #pragma unroll 1
    for (int g = 0; g < G2NKT; ++g) {
        const ushort* Ab = lds + (g & 1) * 8192;
        const ushort* Bb = lds + 16384 + (g & 1) * 12288;

        // issue next-tile stages first (max latency cover; opposite buffer)
        g2_stageA(lds, g + 1, pAs, pAx, wave, 0);
        g2_stageA(lds, g + 1, pAs, pAx, wave, 1);
        g2_stageB(lds, g + 1, pBs, pBx, wave);

        // fragments: compiler schedules ds_reads + fine-grained lgkm waits
        bf16x8 af[4][2], bfr[6][2];
        #pragma unroll
        for (int i = 0; i < 4; ++i) {
            const ushort* p = Ab + (wr + i*16 + lr) * 64;
            af[i][0] = *reinterpret_cast<const bf16x8*>(p + ca0);
            af[i][1] = *reinterpret_cast<const bf16x8*>(p + ca1);
        }
        #pragma unroll
        for (int j = 0; j < 6; ++j) {
            const ushort* p = Bb + (wc + j*16 + lr) * 64;
            bfr[j][0] = *reinterpret_cast<const bf16x8*>(p + ca0);
            bfr[j][1] = *reinterpret_cast<const bf16x8*>(p + ca1);
        }
        __builtin_amdgcn_s_setprio(1);
        #pragma unroll
        for (int ks = 0; ks < 2; ++ks)
            #pragma unroll
            for (int i = 0; i < 4; ++i)
                #pragma unroll
                for (int j = 0; j < 6; ++j)
                    acc[i][j] = __builtin_amdgcn_mfma_f32_16x16x32_bf16(
                                    af[i][ks], bfr[j][ks], acc[i][j], 0, 0, 0);
        __builtin_amdgcn_s_setprio(0);

        // drain next-tile stage (covered by the 48-MFMA burst), flip buffers
        asm volatile("s_waitcnt vmcnt(0)" ::: "memory");
        __builtin_amdgcn_s_barrier();
    }

    // epilogue: lane-local (val,gate) pairs -> gated SiLU -> bf16
    const int vg0 = (n0 + wc) >> 5;
    #pragma unroll
    for (int i = 0; i < 4; ++i)
        #pragma unroll
        for (int p = 0; p < 3; ++p)
            #pragma unroll
            for (int r = 0; r < 4; ++r) {
                int row = m0 + wr + i*16 + quad*4 + r;      // m89-verified C/D map
                int col = (vg0 + p)*16 + lr;
                float v  = acc[i][2*p][r];
                float gt = acc[i][2*p + 1][r];
                float y = v * (gt / (1.f + __expf(-gt)));
                yact[(size_t)row * NACT + col] = f2bf(y);
            }
}

// ---------------------------------------------------------------------------
// Fused token+scan pass 1: one block per (b,k,chunk), 128 thr = 2 waves.
// conv(CK=4)+SiLU+RMSNorm+phase + chunk partial sums; zmem read once
// (rolling-scalar window). r8-proven.
// ---------------------------------------------------------------------------
__global__ __launch_bounds__(128)
void token_scan1(const float* __restrict__ zmem, const float* __restrict__ conv_w,
                 const float* __restrict__ rms_scale, const float* __restrict__ theta_raw,
                 const float* __restrict__ dslopes, const float* __restrict__ sscale,
                 const float* __restrict__ tscale,
                 float* __restrict__ reN, float* __restrict__ imN,
                 float* __restrict__ pwN, float* __restrict__ part)
{
    int blk = blockIdx.x;            // = bk*16 + chunk
    int chunk = blk & (NCHUNK - 1);
    int bk = blk >> 4;
    int k = bk % K_;
    int b = bk / K_;
    int tid = threadIdx.x;
    int h = tid & 63;
    int tt = tid >> 6;               // wave -> token sub-range
    int l0 = chunk * CHLEN + tt * 64;

    int c  = k*H_ + h;
    int cs = DIM_MEM_ + k;

    // hoisted per-thread constants
    float cw0 = conv_w[0*DMK + c], cw1 = conv_w[1*DMK + c];
    float cw2 = conv_w[2*DMK + c], cw3 = conv_w[3*DMK + c];
    float cs0 = conv_w[0*DMK + cs], cs1 = conv_w[1*DMK + cs];
    float cs2 = conv_w[2*DMK + cs], cs3 = conv_w[3*DMK + cs];
    float rs  = rms_scale[h];
    float th  = 0.001f + 2.999f * (1.f / (1.f + __expf(-theta_raw[c])));
    float ts  = tscale[k];
    float scl = sscale[k];
    float slope = log1pf(expf(dslopes[k]));

    const float* zb = zmem + (size_t)(b*L_) * DMK;

    // rolling window carry: z3=row(l-3), z2=row(l-2), z1=row(l-1)
    float z3=0.f, z2=0.f, z1=0.f, s3=0.f, s2=0.f, s1=0.f;
    {
        int ll = l0 - 3;
        if (ll >= 0)     { z3 = zb[(size_t)ll*DMK + c];     s3 = zb[(size_t)ll*DMK + cs]; }
        if (ll + 1 >= 0) { z2 = zb[(size_t)(ll+1)*DMK + c]; s2 = zb[(size_t)(ll+1)*DMK + cs]; }
        if (ll + 2 >= 0) { z1 = zb[(size_t)(ll+2)*DMK + c]; s1 = zb[(size_t)(ll+2)*DMK + cs]; }
    }

    float sre = 0.f, sim = 0.f, spw = 0.f;
    size_t obase = (size_t)blk * (CHLEN*H_) + (size_t)(tt*64)*H_ + h;

    for (int i0 = 0; i0 < 64; i0 += 8) {
        float zl[8], sl[8];
        #pragma unroll
        for (int j = 0; j < 8; ++j) {
            int l = l0 + i0 + j;
            zl[j] = zb[(size_t)l*DMK + c];
            sl[j] = zb[(size_t)l*DMK + cs];
        }
        #pragma unroll
        for (int j = 0; j < 8; ++j) {
            int l = l0 + i0 + j;
            float a3 = zl[j], b3 = sl[j];
            float acc  = cw0*z3 + cw1*z2 + cw2*z1 + cw3*a3;
            float acc2 = cs0*s3 + cs1*s2 + cs2*s1 + cs3*b3;
            z3 = z2; z2 = z1; z1 = a3;       // roll the windows (pure scalars)
            s3 = s2; s2 = s1; s1 = b3;

            float kv = acc / (1.f + __expf(-acc));          // silu (hw exp)
            float ss = kv * kv;
            #pragma unroll
            for (int off = 32; off > 0; off >>= 1)
                ss += __shfl_xor(ss, off, 64);
            float kn  = kv * rsqrtf(ss * (1.f/64.f) + 1e-6f) * rs;
            float phi = tanh_fast(kn * ts) * th;

            float s  = acc2 / (1.f + expf(-acc2));          // match original expf
            float lp = fminf(10.f, fmaxf(-10.f, scl * s));
            float pwv = expf(lp - slope * (float)(L_ - 1 - l));

            float kvw = kn * pwv;
            float rev = kvw * __cosf(phi);
            float imv = kvw * __sinf(phi);
            reN[obase + (size_t)(i0 + j)*H_] = rev;
            imN[obase + (size_t)(i0 + j)*H_] = imv;
            sre += rev; sim += imv; spw += pwv;
            if (h == 0) pwN[(size_t)bk * L_ + l] = pwv;
        }
    }

    // cross-wave combine -> chunk partials (same layout as old scan_sums)
    __shared__ float red[2][64], imd[2][64], pwd[2];
    red[tt][h] = sre; imd[tt][h] = sim;
    if (h == 0) pwd[tt] = spw;
    __syncthreads();
    size_t pb = (size_t)blk * PSTRIDE;
    if (tid < 64) part[pb + tid] = red[0][tid] + red[1][tid];
    else          part[pb + tid] = imd[0][tid - 64] + imd[1][tid - 64];
    if (tid == 0) part[pb + 128] = pwd[0] + pwd[1];
}

// ---------------------------------------------------------------------------
// Scan pass 2 on the chunk-local layout: prefix from partials, emit bf16
// summary. Identical accumulation order to the old scan_final. r8-proven.
// ---------------------------------------------------------------------------
__global__ __launch_bounds__(128)
void scan_final2(const float* __restrict__ pwN, const float* __restrict__ reN,
                 const float* __restrict__ imN, const float* __restrict__ part,
                 ushort* __restrict__ summary)
{
    int blk = blockIdx.x;
    int chunk = blk & (NCHUNK - 1);
    int bk = blk >> 4;
    int k = bk % K_;
    int b = bk / K_;
    int tid = threadIdx.x;
    int h = tid & 63;
    int pi = tid >> 6;
    const float* __restrict__ src = pi ? imN : reN;
    int l0 = chunk * CHLEN;

    float acc = 0.f, dacc = 0.f;
    size_t pb0 = (size_t)(bk * NCHUNK) * PSTRIDE;
    for (int cn = 0; cn < chunk; ++cn) {
        acc  += part[pb0 + (size_t)cn*PSTRIDE + tid];
        dacc += part[pb0 + (size_t)cn*PSTRIDE + 128];
    }

    size_t base  = (size_t)blk * (CHLEN*H_) + h;
    size_t dbase = (size_t)bk * L_ + l0;
    int outch = 2*(k*H_ + h) + pi;
    for (int i0 = 0; i0 < CHLEN; i0 += 8) {
        float v[8], d[8];
        #pragma unroll
        for (int j = 0; j < 8; ++j) {
            v[j] = src[base + (size_t)(i0 + j)*H_];
            d[j] = pwN[dbase + i0 + j];
        }
        #pragma unroll
        for (int j = 0; j < 8; ++j) {
            acc += v[j]; dacc += d[j];
            float inv = 1.f / fmaxf(dacc, 1e-4f);
            summary[((size_t)(b*L_ + l0 + i0 + j))*NSUM + outch] = f2bf(acc * inv);
        }
    }
}

// ---------------------------------------------------------------------------
extern "C" void kernel_launch(void* const* d_in, const int* in_sizes, int n_in,
                              void* d_out, int out_size, void* d_ws, size_t ws_size,
                              hipStream_t stream)
{
    const float* x         = (const float*)d_in[0];
    const float* W_in      = (const float*)d_in[1];
    const float* conv_w    = (const float*)d_in[2];
    const float* rms_scale = (const float*)d_in[3];
    const float* theta_raw = (const float*)d_in[4];
    const float* dslopes   = (const float*)d_in[5];
    const float* sscale    = (const float*)d_in[6];
    const float* tscale    = (const float*)d_in[7];
    const float* W_sw      = (const float*)d_in[8];
    const float* W_out     = (const float*)d_in[9];
    float* out = (float*)d_out;
    char* ws   = (char*)d_ws;

    // Workspace (byte offsets, all 256-aligned). Peak ~115.4 MB (< proven 127).
    float*  zmem    = (float*) (ws + 0);           // NT*780 f32   = 25,559,040 B
    ushort* summary = (ushort*)(ws + 0);           // alias (zmem dead): 25,165,824 B
    float*  pw      = (float*) (ws + 25559040);    //   393,216 B  [bk][l]
    float*  re      = (float*) (ws + 25952256);    // 25,165,824 B [blk][tok][h]
    float*  im      = (float*) (ws + 51118080);    // 25,165,824 B
    ushort* yact    = (ushort*)(ws + 25952256);    // alias re+im (dead): 37,748,736 B
    float*  part    = (float*) (ws + 76283904);    //   405,504 B
    ushort* xb      = (ushort*)(ws + 76689408);    // 12,582,912 B
    ushort* WiCat   = (ushort*)(ws + 89272320);    //  7,077,888 B  [4608][768]  val/gate interleaved
    ushort* WsCat   = (ushort*)(ws + 96350208);    // 14,155,776 B  [4608][1536] val/gate interleaved
    ushort* WoT     = (ushort*)(ws + 110505984);   //  3,538,944 B  [768][2304]
    ushort* WimT    = (ushort*)(ws + 114044928);   //  1,376,256 B  [896][768] (pad)

    // ---- merged prep job table ----
    PrepJobs J{};
    J.W[0]=W_in;  J.out[0]=WiCat; J.ldw[0]=5388; J.Kd[0]=768;  J.colbase[0]=780; J.remap[0]=1; J.ntx[0]=144;
    J.W[1]=W_sw;  J.out[1]=WsCat; J.ldw[1]=4608; J.Kd[1]=1536; J.colbase[1]=0;   J.remap[1]=1; J.ntx[1]=144;
    J.W[2]=W_out; J.out[2]=WoT;   J.ldw[2]=768;  J.Kd[2]=2304; J.colbase[2]=0;   J.remap[2]=0; J.ntx[2]=24;
    J.W[3]=W_in;  J.out[3]=WimT;  J.ldw[3]=5388; J.Kd[3]=768;  J.colbase[3]=0;   J.remap[3]=0; J.ntx[3]=28;
    int tiles[4] = {144*24, 144*48, 24*72, 28*24};
    J.start[0] = 0;
    for (int j = 0; j < 4; ++j) J.start[j+1] = J.start[j] + tiles[j];
    J.start[5] = J.start[4];
    J.start[6] = J.start[4];
    J.cast_in = x; J.cast_out = xb; J.n4 = NT*D_/4;
    int nblk = J.start[6] + (J.n4 + 255)/256;

    dim3 blk(256);
    // 0) all preps in one launch
    prep_all<<<dim3(nblk), blk, 0, stream>>>(J);
    // 1) z_mem = x @ W_in[:, :780]  (1-phase pipelined MFMA, col-guarded)
    gemm13_1ph<<<dim3(7, 64), blk, 0, stream>>>(xb, WimT, zmem, 768, 780, 780);
    // 2) fused conv+silu+rmsnorm+phase + chunk partial sums (1x zmem read)
    token_scan1<<<dim3(B_*K_*NCHUNK), dim3(128), 0, stream>>>(
        zmem, conv_w, rms_scale, theta_raw, dslopes, sscale, tscale,
        re, im, pw, part);
    // 3) prefix + emit summary (bf16)
    scan_final2<<<dim3(B_*K_*NCHUNK), dim3(128), 0, stream>>>(pw, re, im, part, summary);
    // 4) fused spectral+skip single-phase pipelined GEMM, 2 blocks/CU -> yact
    gemm2_1ph<<<dim3(24, 64), dim3(256), 0, stream>>>(summary, xb, WsCat, WiCat, yact);
    // 5) out = yact @ W_out  (1-phase pipelined MFMA)
    gemm13_1ph<<<dim3(6, 64), blk, 0, stream>>>(yact, WoT, out, 2304, 768, 768);
}

// Round 10
// 389.676 us; speedup vs baseline: 1.5315x; 1.0125x over previous
//
#include <hip/hip_runtime.h>
#include <hip/hip_bf16.h>

// Problem constants (B,L,D)=(4,2048,768), K=12, M=1, CK=4, H=64
#define B_       4
#define L_       2048
#define D_       768
#define K_       12
#define H_       64
#define CK_      4
#define DIM_MEM_ 768
#define DMK      780        // DIM_MEM + K
#define NT       (B_*L_)    // 8192 tokens
#define NSUM     1536       // 2*K*H  (summary width)
#define NACT     2304       // K*192  (y_act width)
#define NCHUNK   16
#define CHLEN    (L_/NCHUNK)  // 128
#define PSTRIDE  132

typedef __attribute__((ext_vector_type(8))) short          bf16x8;
typedef __attribute__((ext_vector_type(8))) unsigned short u16x8;
typedef __attribute__((ext_vector_type(4))) float          f32x4;

__device__ __forceinline__ ushort f2bf(float v) {
    __hip_bfloat16 h = __float2bfloat16(v);
    return *reinterpret_cast<ushort*>(&h);
}
// fast tanh via hw exp; safe for any x
__device__ __forceinline__ float tanh_fast(float x) {
    float t = __expf(-2.f * fabsf(x));
    float r = (1.f - t) / (1.f + t);
    return copysignf(r, x);
}

// ---------------------------------------------------------------------------
// Merged prep: transpose-cast jobs (32x32 LDS tiles) + x->bf16 cast.
// remap==1: interleaved val/gate layout for the fused spectral GEMM:
//   virtual col vc: grp=vc>>5, which=(vc>>4)&1, nn=grp*16+(vc&15)
//   orig col = colbase + (nn/192)*384 + which*192 + (nn%192)
// ---------------------------------------------------------------------------
struct PrepJobs {
    const float* W[6];
    ushort*      out[6];
    int ldw[6], Kd[6], colbase[6], remap[6], ntx[6];
    int start[7];
    const float* cast_in;
    ushort*      cast_out;
    int n4;
};

__global__ __launch_bounds__(256)
void prep_all(PrepJobs J)
{
    int blk = blockIdx.x;
    if (blk >= J.start[6]) {                       // cast job
        int i = (blk - J.start[6]) * 256 + threadIdx.x;
        if (i < J.n4) {
            float4 v = reinterpret_cast<const float4*>(J.cast_in)[i];
            ushort4 o;
            o.x = f2bf(v.x); o.y = f2bf(v.y); o.z = f2bf(v.z); o.w = f2bf(v.w);
            reinterpret_cast<ushort4*>(J.cast_out)[i] = o;
        }
        return;
    }
    int j = 0;
    while (blk >= J.start[j + 1]) ++j;
    int rel = blk - J.start[j];
    int ntx = J.ntx[j];
    int n0 = (rel % ntx) * 32, k0 = (rel / ntx) * 32;
    const float* W = J.W[j];
    int ldw = J.ldw[j], Kd = J.Kd[j], colbase = J.colbase[j], remap = J.remap[j];
    ushort* out = J.out[j];

    __shared__ float tile[32][33];
    int tx = threadIdx.x & 31, ty = threadIdx.x >> 5;
    int n = n0 + tx;
    int c;
    if (remap) {
        int grp = n >> 5, which = (n >> 4) & 1, nn = (grp << 4) + (n & 15);
        c = colbase + (nn / 192) * 384 + which * 192 + (nn % 192);
    } else {
        c = colbase + n;
    }
    #pragma unroll
    for (int r = 0; r < 4; ++r)
        tile[ty + r*8][tx] = W[(size_t)(k0 + ty + r*8) * ldw + c];
    __syncthreads();
    #pragma unroll
    for (int r = 0; r < 4; ++r)
        out[(size_t)(n0 + ty + r*8) * Kd + k0 + tx] = f2bf(tile[tx][ty + r*8]);
}

// ---------------------------------------------------------------------------
// global_load_lds staging macro (width 16)
// ---------------------------------------------------------------------------
#define GLOAD16(gp, dp) __builtin_amdgcn_global_load_lds( \
    (__attribute__((address_space(1))) const void*)(gp),  \
    (__attribute__((address_space(3))) void*)(dp), 16, 0, 0)

// ---------------------------------------------------------------------------
// bf16 MFMA GEMM, 1-phase pipelined + 2 blocks/CU + bijective XCD swizzle.
// C[M,N] f32 = A[M,K] * BT[N,K]^T, col<N write guard. 128x128 tile, BK=64,
// 4 waves. Swizzle (T1): hardware block id round-robins XCDs; remap work so
// each XCD owns nwg/8 CONSECUTIVE logical tiles -> co-resident blocks share
// A-panels in that XCD's private L2 (cuts stage-load latency the end-of-tile
// vmcnt(0) drain exposes). Requires nwg%8==0 (call sites: 448, 384).
// ---------------------------------------------------------------------------
__device__ __forceinline__ void g13_stage(ushort* dst, const ushort* src, int kd)
{
    #pragma unroll
    for (int s = 0; s < 4; ++s)
        GLOAD16(src + (size_t)(32*s)*kd, dst + 2048*s);
}

__global__ __launch_bounds__(256, 2)
void gemm13_1ph(const ushort* __restrict__ A, const ushort* __restrict__ BT,
                float* __restrict__ C, int Kd, int N, int ldc)
{
    // LDS (ushort units): A bufs @0,@8192 (128x64 each, 16 KB);
    //                     B bufs @16384,@24576. Total 64 KB.
    __shared__ ushort lds[32768];
    const int tid  = threadIdx.x;
    const int lane = tid & 63, wave = tid >> 6;
    const int lr = lane & 15, quad = lane >> 4, rx = lr & 7;
    const int wr = (wave >> 1) * 64, wc = (wave & 1) * 64;

    // bijective chunked XCD swizzle (nwg % 8 == 0 at all call sites)
    const int nwgx = gridDim.x;
    const int orig = blockIdx.x + blockIdx.y * nwgx;
    const int cpx  = (nwgx * gridDim.y) >> 3;
    const int swz  = (orig & 7) * cpx + (orig >> 3);
    const int m0 = (swz / nwgx) * 128, n0 = (swz % nwgx) * 128;
    const int NKT = Kd >> 6;

    // staging source pointers (pre-swizzled chunk)
    const int sr = tid >> 3;             // 0..31
    const int sc = (tid & 7) ^ (sr & 7);
    const ushort* pA = A  + (size_t)(m0 + sr) * Kd + sc * 8;
    const ushort* pB = BT + (size_t)(n0 + sr) * Kd + sc * 8;

    f32x4 acc[4][4] = {};
    const int ca0 = (quad ^ rx) * 8;
    const int ca1 = ((4 + quad) ^ rx) * 8;

    // prologue: stage tile 0 into buf 0; drain, barrier.
    g13_stage(lds + wave*512,         pA, Kd);
    g13_stage(lds + 16384 + wave*512, pB, Kd);
    asm volatile("s_waitcnt vmcnt(0)" ::: "memory");
    __builtin_amdgcn_s_barrier();

    #pragma unroll 1
    for (int g = 0; g < NKT; ++g) {
        const ushort* Ab = lds + (g & 1) * 8192;
        const ushort* Bb = lds + 16384 + (g & 1) * 8192;

        // issue next-tile stages first (opposite buffer; clamp src at last)
        int nk = (g + 1 < NKT) ? g + 1 : NKT - 1;
        g13_stage(lds + ((g + 1) & 1) * 8192 + wave*512,         pA + nk*64, Kd);
        g13_stage(lds + 16384 + ((g + 1) & 1) * 8192 + wave*512, pB + nk*64, Kd);

        bf16x8 af[4][2], bf[4][2];
        #pragma unroll
        for (int i = 0; i < 4; ++i) {
            const ushort* p = Ab + (wr + i*16 + lr) * 64;
            af[i][0] = *reinterpret_cast<const bf16x8*>(p + ca0);
            af[i][1] = *reinterpret_cast<const bf16x8*>(p + ca1);
        }
        #pragma unroll
        for (int j = 0; j < 4; ++j) {
            const ushort* p = Bb + (wc + j*16 + lr) * 64;
            bf[j][0] = *reinterpret_cast<const bf16x8*>(p + ca0);
            bf[j][1] = *reinterpret_cast<const bf16x8*>(p + ca1);
        }
        __builtin_amdgcn_s_setprio(1);
        #pragma unroll
        for (int ks = 0; ks < 2; ++ks)
            #pragma unroll
            for (int i = 0; i < 4; ++i)
                #pragma unroll
                for (int j = 0; j < 4; ++j)
                    acc[i][j] = __builtin_amdgcn_mfma_f32_16x16x32_bf16(
                                    af[i][ks], bf[j][ks], acc[i][j], 0, 0, 0);
        __builtin_amdgcn_s_setprio(0);

        asm volatile("s_waitcnt vmcnt(0)" ::: "memory");
        __builtin_amdgcn_s_barrier();
    }

    #pragma unroll
    for (int i = 0; i < 4; ++i)
        #pragma unroll
        for (int j = 0; j < 4; ++j)
            #pragma unroll
            for (int r = 0; r < 4; ++r) {
                int row = m0 + wr + i*16 + quad*4 + r;      // m89-verified C/D map
                int col = n0 + wc + j*16 + lr;
                if (col < N)
                    C[(size_t)row * ldc + col] = acc[i][j][r];
            }
}

// ---------------------------------------------------------------------------
// Fused spectral+skip GEMM, single-phase pipelined + 2 blocks/CU (r3/r8/r9
// proven: ~147us, MfmaUtil 56%, VGPR 100) + bijective XCD swizzle (nwg=1536,
// 1536%8==0; each XCD gets 192 consecutive logical tiles = 8 m-panels).
// ---------------------------------------------------------------------------
#define G2NKT 36   // 24 k-tiles of summary (K=1536) + 12 of x (K=768)

__device__ __forceinline__ void g2_stageA(ushort* lds_, int kt,
                                          const ushort* pAs, const ushort* pAx,
                                          int wave, int part)
{
    int ktc = kt > (G2NKT-1) ? (G2NKT-1) : kt;   // clamp src; dest parity uses kt
    const ushort* g; size_t kd;
    if (ktc < 24) { g = pAs + ktc*64;      kd = 1536; }
    else          { g = pAx + (ktc-24)*64; kd = 768;  }
    g += (size_t)(part * 64) * kd;               // rows part*64 .. part*64+63
    ushort* d = lds_ + (kt & 1) * 8192 + part * 4096 + wave * 512;
    GLOAD16(g,           d);
    GLOAD16(g + 32*kd,   d + 2048);
}

__device__ __forceinline__ void g2_stageB(ushort* lds_, int kt,
                                          const ushort* pBs, const ushort* pBx,
                                          int wave)
{
    int ktc = kt > (G2NKT-1) ? (G2NKT-1) : kt;
    const ushort* g; size_t kd;
    if (ktc < 24) { g = pBs + ktc*64;      kd = 1536; }
    else          { g = pBx + (ktc-24)*64; kd = 768;  }
    ushort* d = lds_ + 16384 + (kt & 1) * 12288 + wave * 512;
    #pragma unroll
    for (int s = 0; s < 6; ++s)
        GLOAD16(g + (size_t)(32*s)*kd, d + 2048*s);
}

__global__ __launch_bounds__(256, 2)
void gemm2_1ph(const ushort* __restrict__ Sm, const ushort* __restrict__ Xb,
               const ushort* __restrict__ WsC, const ushort* __restrict__ WiC,
               ushort* __restrict__ yact)
{
    // LDS (ushort units): A bufs @0 and @8192 (128x64 each);
    //                     B bufs @16384 and @28672 (192x64 each). 80 KiB.
    __shared__ ushort lds[40960];
    const int tid  = threadIdx.x;
    const int lane = tid & 63, wave = tid >> 6;      // wave 0..3
    const int lr = lane & 15, quad = lane >> 4, rx = lr & 7;
    const int wr = (wave >> 1) * 64;     // 0,64
    const int wc = (wave & 1) * 96;      // 0,96

    // bijective chunked XCD swizzle: nwg = 24*64 = 1536, cpx = 192
    const int orig = blockIdx.x + blockIdx.y * 24;
    const int swz  = (orig & 7) * 192 + (orig >> 3);
    const int m0 = (swz / 24) * 128, n0 = (swz % 24) * 192;

    // staging source pointers (pre-swizzled chunk): LDS[row][c] holds global
    // chunk c^(row&7); reader XORs the same way.
    const int sr = tid >> 3;             // 0..31
    const int sc = (tid & 7) ^ (sr & 7);
    const ushort* pAs = Sm  + (size_t)(m0 + sr) * 1536 + sc * 8;
    const ushort* pAx = Xb  + (size_t)(m0 + sr) * 768  + sc * 8;
    const ushort* pBs = WsC + (size_t)(n0 + sr) * 1536 + sc * 8;
    const ushort* pBx = WiC + (size_t)(n0 + sr) * 768  + sc * 8;

    f32x4 acc[4][6] = {};
    const int ca0 = (quad ^ rx) * 8;
    const int ca1 = ((4 + quad) ^ rx) * 8;

    // prologue: A(0) + B(0) = 10 loads; drain, barrier.
    g2_stageA(lds, 0, pAs, pAx, wave, 0);
    g2_stageA(lds, 0, pAs, pAx, wave, 1);
    g2_stageB(lds, 0, pBs, pBx, wave);
    asm volatile("s_waitcnt vmcnt(0)" ::: "memory");
    __builtin_amdgcn_s_barrier();

    #pragma unroll 1
    for (int g = 0; g < G2NKT; ++g) {
        const ushort* Ab = lds + (g & 1) * 8192;
        const ushort* Bb = lds + 16384 + (g & 1) * 12288;

        // issue next-tile stages first (max latency cover; opposite buffer)
        g2_stageA(lds, g + 1, pAs, pAx, wave, 0);
        g2_stageA(lds, g + 1, pAs, pAx, wave, 1);
        g2_stageB(lds, g + 1, pBs, pBx, wave);

        // fragments: compiler schedules ds_reads + fine-grained lgkm waits
        bf16x8 af[4][2], bfr[6][2];
        #pragma unroll
        for (int i = 0; i < 4; ++i) {
            const ushort* p = Ab + (wr + i*16 + lr) * 64;
            af[i][0] = *reinterpret_cast<const bf16x8*>(p + ca0);
            af[i][1] = *reinterpret_cast<const bf16x8*>(p + ca1);
        }
        #pragma unroll
        for (int j = 0; j < 6; ++j) {
            const ushort* p = Bb + (wc + j*16 + lr) * 64;
            bfr[j][0] = *reinterpret_cast<const bf16x8*>(p + ca0);
            bfr[j][1] = *reinterpret_cast<const bf16x8*>(p + ca1);
        }
        __builtin_amdgcn_s_setprio(1);
        #pragma unroll
        for (int ks = 0; ks < 2; ++ks)
            #pragma unroll
            for (int i = 0; i < 4; ++i)
                #pragma unroll
                for (int j = 0; j < 6; ++j)
                    acc[i][j] = __builtin_amdgcn_mfma_f32_16x16x32_bf16(
                                    af[i][ks], bfr[j][ks], acc[i][j], 0, 0, 0);
        __builtin_amdgcn_s_setprio(0);

        // drain next-tile stage (covered by the 48-MFMA burst), flip buffers
        asm volatile("s_waitcnt vmcnt(0)" ::: "memory");
        __builtin_amdgcn_s_barrier();
    }

    // epilogue: lane-local (val,gate) pairs -> gated SiLU -> bf16
    const int vg0 = (n0 + wc) >> 5;
    #pragma unroll
    for (int i = 0; i < 4; ++i)
        #pragma unroll
        for (int p = 0; p < 3; ++p)
            #pragma unroll
            for (int r = 0; r < 4; ++r) {
                int row = m0 + wr + i*16 + quad*4 + r;      // m89-verified C/D map
                int col = (vg0 + p)*16 + lr;
                float v  = acc[i][2*p][r];
                float gt = acc[i][2*p + 1][r];
                float y = v * (gt / (1.f + __expf(-gt)));
                yact[(size_t)row * NACT + col] = f2bf(y);
            }
}

// ---------------------------------------------------------------------------
// Fused token+scan pass 1: one block per (b,k,chunk), 128 thr = 2 waves.
// conv(CK=4)+SiLU+RMSNorm+phase + chunk partial sums; zmem read once
// (rolling-scalar window). r8/r9-proven.
// ---------------------------------------------------------------------------
__global__ __launch_bounds__(128)
void token_scan1(const float* __restrict__ zmem, const float* __restrict__ conv_w,
                 const float* __restrict__ rms_scale, const float* __restrict__ theta_raw,
                 const float* __restrict__ dslopes, const float* __restrict__ sscale,
                 const float* __restrict__ tscale,
                 float* __restrict__ reN, float* __restrict__ imN,
                 float* __restrict__ pwN, float* __restrict__ part)
{
    int blk = blockIdx.x;            // = bk*16 + chunk
    int chunk = blk & (NCHUNK - 1);
    int bk = blk >> 4;
    int k = bk % K_;
    int b = bk / K_;
    int tid = threadIdx.x;
    int h = tid & 63;
    int tt = tid >> 6;               // wave -> token sub-range
    int l0 = chunk * CHLEN + tt * 64;

    int c  = k*H_ + h;
    int cs = DIM_MEM_ + k;

    // hoisted per-thread constants
    float cw0 = conv_w[0*DMK + c], cw1 = conv_w[1*DMK + c];
    float cw2 = conv_w[2*DMK + c], cw3 = conv_w[3*DMK + c];
    float cs0 = conv_w[0*DMK + cs], cs1 = conv_w[1*DMK + cs];
    float cs2 = conv_w[2*DMK + cs], cs3 = conv_w[3*DMK + cs];
    float rs  = rms_scale[h];
    float th  = 0.001f + 2.999f * (1.f / (1.f + __expf(-theta_raw[c])));
    float ts  = tscale[k];
    float scl = sscale[k];
    float slope = log1pf(expf(dslopes[k]));

    const float* zb = zmem + (size_t)(b*L_) * DMK;

    // rolling window carry: z3=row(l-3), z2=row(l-2), z1=row(l-1)
    float z3=0.f, z2=0.f, z1=0.f, s3=0.f, s2=0.f, s1=0.f;
    {
        int ll = l0 - 3;
        if (ll >= 0)     { z3 = zb[(size_t)ll*DMK + c];     s3 = zb[(size_t)ll*DMK + cs]; }
        if (ll + 1 >= 0) { z2 = zb[(size_t)(ll+1)*DMK + c]; s2 = zb[(size_t)(ll+1)*DMK + cs]; }
        if (ll + 2 >= 0) { z1 = zb[(size_t)(ll+2)*DMK + c]; s1 = zb[(size_t)(ll+2)*DMK + cs]; }
    }

    float sre = 0.f, sim = 0.f, spw = 0.f;
    size_t obase = (size_t)blk * (CHLEN*H_) + (size_t)(tt*64)*H_ + h;

    for (int i0 = 0; i0 < 64; i0 += 8) {
        float zl[8], sl[8];
        #pragma unroll
        for (int j = 0; j < 8; ++j) {
            int l = l0 + i0 + j;
            zl[j] = zb[(size_t)l*DMK + c];
            sl[j] = zb[(size_t)l*DMK + cs];
        }
        #pragma unroll
        for (int j = 0; j < 8; ++j) {
            int l = l0 + i0 + j;
            float a3 = zl[j], b3 = sl[j];
            float acc  = cw0*z3 + cw1*z2 + cw2*z1 + cw3*a3;
            float acc2 = cs0*s3 + cs1*s2 + cs2*s1 + cs3*b3;
            z3 = z2; z2 = z1; z1 = a3;       // roll the windows (pure scalars)
            s3 = s2; s2 = s1; s1 = b3;

            float kv = acc / (1.f + __expf(-acc));          // silu (hw exp)
            float ss = kv * kv;
            #pragma unroll
            for (int off = 32; off > 0; off >>= 1)
                ss += __shfl_xor(ss, off, 64);
            float kn  = kv * rsqrtf(ss * (1.f/64.f) + 1e-6f) * rs;
            float phi = tanh_fast(kn * ts) * th;

            float s  = acc2 / (1.f + expf(-acc2));          // match original expf
            float lp = fminf(10.f, fmaxf(-10.f, scl * s));
            float pwv = expf(lp - slope * (float)(L_ - 1 - l));

            float kvw = kn * pwv;
            float rev = kvw * __cosf(phi);
            float imv = kvw * __sinf(phi);
            reN[obase + (size_t)(i0 + j)*H_] = rev;
            imN[obase + (size_t)(i0 + j)*H_] = imv;
            sre += rev; sim += imv; spw += pwv;
            if (h == 0) pwN[(size_t)bk * L_ + l] = pwv;
        }
    }

    // cross-wave combine -> chunk partials (same layout as old scan_sums)
    __shared__ float red[2][64], imd[2][64], pwd[2];
    red[tt][h] = sre; imd[tt][h] = sim;
    if (h == 0) pwd[tt] = spw;
    __syncthreads();
    size_t pb = (size_t)blk * PSTRIDE;
    if (tid < 64) part[pb + tid] = red[0][tid] + red[1][tid];
    else          part[pb + tid] = imd[0][tid - 64] + imd[1][tid - 64];
    if (tid == 0) part[pb + 128] = pwd[0] + pwd[1];
}

// ---------------------------------------------------------------------------
// Scan pass 2 on the chunk-local layout: prefix from partials, emit bf16
// summary. Identical accumulation order to the old scan_final. r8/r9-proven.
// ---------------------------------------------------------------------------
__global__ __launch_bounds__(128)
void scan_final2(const float* __restrict__ pwN, const float* __restrict__ reN,
                 const float* __restrict__ imN, const float* __restrict__ part,
                 ushort* __restrict__ summary)
{
    int blk = blockIdx.x;
    int chunk = blk & (NCHUNK - 1);
    int bk = blk >> 4;
    int k = bk % K_;
    int b = bk / K_;
    int tid = threadIdx.x;
    int h = tid & 63;
    int pi = tid >> 6;
    const float* __restrict__ src = pi ? imN : reN;
    int l0 = chunk * CHLEN;

    float acc = 0.f, dacc = 0.f;
    size_t pb0 = (size_t)(bk * NCHUNK) * PSTRIDE;
    for (int cn = 0; cn < chunk; ++cn) {
        acc  += part[pb0 + (size_t)cn*PSTRIDE + tid];
        dacc += part[pb0 + (size_t)cn*PSTRIDE + 128];
    }

    size_t base  = (size_t)blk * (CHLEN*H_) + h;
    size_t dbase = (size_t)bk * L_ + l0;
    int outch = 2*(k*H_ + h) + pi;
    for (int i0 = 0; i0 < CHLEN; i0 += 8) {
        float v[8], d[8];
        #pragma unroll
        for (int j = 0; j < 8; ++j) {
            v[j] = src[base + (size_t)(i0 + j)*H_];
            d[j] = pwN[dbase + i0 + j];
        }
        #pragma unroll
        for (int j = 0; j < 8; ++j) {
            acc += v[j]; dacc += d[j];
            float inv = 1.f / fmaxf(dacc, 1e-4f);
            summary[((size_t)(b*L_ + l0 + i0 + j))*NSUM + outch] = f2bf(acc * inv);
        }
    }
}

// ---------------------------------------------------------------------------
extern "C" void kernel_launch(void* const* d_in, const int* in_sizes, int n_in,
                              void* d_out, int out_size, void* d_ws, size_t ws_size,
                              hipStream_t stream)
{
    const float* x         = (const float*)d_in[0];
    const float* W_in      = (const float*)d_in[1];
    const float* conv_w    = (const float*)d_in[2];
    const float* rms_scale = (const float*)d_in[3];
    const float* theta_raw = (const float*)d_in[4];
    const float* dslopes   = (const float*)d_in[5];
    const float* sscale    = (const float*)d_in[6];
    const float* tscale    = (const float*)d_in[7];
    const float* W_sw      = (const float*)d_in[8];
    const float* W_out     = (const float*)d_in[9];
    float* out = (float*)d_out;
    char* ws   = (char*)d_ws;

    // Workspace (byte offsets, all 256-aligned). Peak ~115.4 MB (< proven 127).
    float*  zmem    = (float*) (ws + 0);           // NT*780 f32   = 25,559,040 B
    ushort* summary = (ushort*)(ws + 0);           // alias (zmem dead): 25,165,824 B
    float*  pw      = (float*) (ws + 25559040);    //   393,216 B  [bk][l]
    float*  re      = (float*) (ws + 25952256);    // 25,165,824 B [blk][tok][h]
    float*  im      = (float*) (ws + 51118080);    // 25,165,824 B
    ushort* yact    = (ushort*)(ws + 25952256);    // alias re+im (dead): 37,748,736 B
    float*  part    = (float*) (ws + 76283904);    //   405,504 B
    ushort* xb      = (ushort*)(ws + 76689408);    // 12,582,912 B
    ushort* WiCat   = (ushort*)(ws + 89272320);    //  7,077,888 B  [4608][768]  val/gate interleaved
    ushort* WsCat   = (ushort*)(ws + 96350208);    // 14,155,776 B  [4608][1536] val/gate interleaved
    ushort* WoT     = (ushort*)(ws + 110505984);   //  3,538,944 B  [768][2304]
    ushort* WimT    = (ushort*)(ws + 114044928);   //  1,376,256 B  [896][768] (pad)

    // ---- merged prep job table ----
    PrepJobs J{};
    J.W[0]=W_in;  J.out[0]=WiCat; J.ldw[0]=5388; J.Kd[0]=768;  J.colbase[0]=780; J.remap[0]=1; J.ntx[0]=144;
    J.W[1]=W_sw;  J.out[1]=WsCat; J.ldw[1]=4608; J.Kd[1]=1536; J.colbase[1]=0;   J.remap[1]=1; J.ntx[1]=144;
    J.W[2]=W_out; J.out[2]=WoT;   J.ldw[2]=768;  J.Kd[2]=2304; J.colbase[2]=0;   J.remap[2]=0; J.ntx[2]=24;
    J.W[3]=W_in;  J.out[3]=WimT;  J.ldw[3]=5388; J.Kd[3]=768;  J.colbase[3]=0;   J.remap[3]=0; J.ntx[3]=28;
    int tiles[4] = {144*24, 144*48, 24*72, 28*24};
    J.start[0] = 0;
    for (int j = 0; j < 4; ++j) J.start[j+1] = J.start[j] + tiles[j];
    J.start[5] = J.start[4];
    J.start[6] = J.start[4];
    J.cast_in = x; J.cast_out = xb; J.n4 = NT*D_/4;
    int nblk = J.start[6] + (J.n4 + 255)/256;

    dim3 blk(256);
    // 0) all preps in one launch
    prep_all<<<dim3(nblk), blk, 0, stream>>>(J);
    // 1) z_mem = x @ W_in[:, :780]  (1-phase pipelined MFMA, col-guarded)
    gemm13_1ph<<<dim3(7, 64), blk, 0, stream>>>(xb, WimT, zmem, 768, 780, 780);
    // 2) fused conv+silu+rmsnorm+phase + chunk partial sums (1x zmem read)
    token_scan1<<<dim3(B_*K_*NCHUNK), dim3(128), 0, stream>>>(
        zmem, conv_w, rms_scale, theta_raw, dslopes, sscale, tscale,
        re, im, pw, part);
    // 3) prefix + emit summary (bf16)
    scan_final2<<<dim3(B_*K_*NCHUNK), dim3(128), 0, stream>>>(pw, re, im, part, summary);
    // 4) fused spectral+skip single-phase pipelined GEMM + XCD swizzle -> yact
    gemm2_1ph<<<dim3(24, 64), dim3(256), 0, stream>>>(summary, xb, WsCat, WiCat, yact);
    // 5) out = yact @ W_out  (1-phase pipelined MFMA)
    gemm13_1ph<<<dim3(6, 64), blk, 0, stream>>>(yact, WoT, out, 2304, 768, 768);
}

// Round 11
// 375.785 us; speedup vs baseline: 1.5881x; 1.0370x over previous
//
#include <hip/hip_runtime.h>
#include <hip/hip_bf16.h>

// Problem constants (B,L,D)=(4,2048,768), K=12, M=1, CK=4, H=64
#define B_       4
#define L_       2048
#define D_       768
#define K_       12
#define H_       64
#define CK_      4
#define DIM_MEM_ 768
#define DMK      780        // DIM_MEM + K
#define NT       (B_*L_)    // 8192 tokens
#define NSUM     1536       // 2*K*H  (summary width)
#define NACT     2304       // K*192  (y_act width)
#define NCHUNK   16
#define CHLEN    (L_/NCHUNK)  // 128
#define PSTRIDE  132

typedef __attribute__((ext_vector_type(8))) short          bf16x8;
typedef __attribute__((ext_vector_type(8))) unsigned short u16x8;
typedef __attribute__((ext_vector_type(4))) float          f32x4;

__device__ __forceinline__ ushort f2bf(float v) {
    __hip_bfloat16 h = __float2bfloat16(v);
    return *reinterpret_cast<ushort*>(&h);
}
// fast tanh via hw exp; safe for any x
__device__ __forceinline__ float tanh_fast(float x) {
    float t = __expf(-2.f * fabsf(x));
    float r = (1.f - t) / (1.f + t);
    return copysignf(r, x);
}

// ---------------------------------------------------------------------------
// Merged prep: transpose-cast jobs (32x32 LDS tiles) + x->bf16 cast.
// remap==1: interleaved val/gate layout for the fused spectral GEMM:
//   virtual col vc: grp=vc>>5, which=(vc>>4)&1, nn=grp*16+(vc&15)
//   orig col = colbase + (nn/192)*384 + which*192 + (nn%192)
// ---------------------------------------------------------------------------
struct PrepJobs {
    const float* W[6];
    ushort*      out[6];
    int ldw[6], Kd[6], colbase[6], remap[6], ntx[6];
    int start[7];
    const float* cast_in;
    ushort*      cast_out;
    int n4;
};

__global__ __launch_bounds__(256)
void prep_all(PrepJobs J)
{
    int blk = blockIdx.x;
    if (blk >= J.start[6]) {                       // cast job
        int i = (blk - J.start[6]) * 256 + threadIdx.x;
        if (i < J.n4) {
            float4 v = reinterpret_cast<const float4*>(J.cast_in)[i];
            ushort4 o;
            o.x = f2bf(v.x); o.y = f2bf(v.y); o.z = f2bf(v.z); o.w = f2bf(v.w);
            reinterpret_cast<ushort4*>(J.cast_out)[i] = o;
        }
        return;
    }
    int j = 0;
    while (blk >= J.start[j + 1]) ++j;
    int rel = blk - J.start[j];
    int ntx = J.ntx[j];
    int n0 = (rel % ntx) * 32, k0 = (rel / ntx) * 32;
    const float* W = J.W[j];
    int ldw = J.ldw[j], Kd = J.Kd[j], colbase = J.colbase[j], remap = J.remap[j];
    ushort* out = J.out[j];

    __shared__ float tile[32][33];
    int tx = threadIdx.x & 31, ty = threadIdx.x >> 5;
    int n = n0 + tx;
    int c;
    if (remap) {
        int grp = n >> 5, which = (n >> 4) & 1, nn = (grp << 4) + (n & 15);
        c = colbase + (nn / 192) * 384 + which * 192 + (nn % 192);
    } else {
        c = colbase + n;
    }
    #pragma unroll
    for (int r = 0; r < 4; ++r)
        tile[ty + r*8][tx] = W[(size_t)(k0 + ty + r*8) * ldw + c];
    __syncthreads();
    #pragma unroll
    for (int r = 0; r < 4; ++r)
        out[(size_t)(n0 + ty + r*8) * Kd + k0 + tx] = f2bf(tile[tx][ty + r*8]);
}

// ---------------------------------------------------------------------------
// global_load_lds staging macro (width 16)
// ---------------------------------------------------------------------------
#define GLOAD16(gp, dp) __builtin_amdgcn_global_load_lds( \
    (__attribute__((address_space(1))) const void*)(gp),  \
    (__attribute__((address_space(3))) void*)(dp), 16, 0, 0)

// ---------------------------------------------------------------------------
// bf16 MFMA GEMM, 1-phase pipelined + 2 blocks/CU + bijective XCD swizzle.
// C[M,N] f32 = A[M,K] * BT[N,K]^T, col<N write guard. 128x128 tile, BK=64,
// 4 waves. Swizzle (T1) KEPT here (r10: helped ~20us combined): B operand is
// tiny (<=1.4 MB, L2-resident per XCD) so per-XCD m-row chunking wins A-panel
// L2 hits at no B cost. Requires nwg%8==0 (call sites: 448, 384).
// ---------------------------------------------------------------------------
__device__ __forceinline__ void g13_stage(ushort* dst, const ushort* src, int kd)
{
    #pragma unroll
    for (int s = 0; s < 4; ++s)
        GLOAD16(src + (size_t)(32*s)*kd, dst + 2048*s);
}

__global__ __launch_bounds__(256, 2)
void gemm13_1ph(const ushort* __restrict__ A, const ushort* __restrict__ BT,
                float* __restrict__ C, int Kd, int N, int ldc)
{
    // LDS (ushort units): A bufs @0,@8192 (128x64 each, 16 KB);
    //                     B bufs @16384,@24576. Total 64 KB.
    __shared__ ushort lds[32768];
    const int tid  = threadIdx.x;
    const int lane = tid & 63, wave = tid >> 6;
    const int lr = lane & 15, quad = lane >> 4, rx = lr & 7;
    const int wr = (wave >> 1) * 64, wc = (wave & 1) * 64;

    // bijective chunked XCD swizzle (nwg % 8 == 0 at all call sites)
    const int nwgx = gridDim.x;
    const int orig = blockIdx.x + blockIdx.y * nwgx;
    const int cpx  = (nwgx * gridDim.y) >> 3;
    const int swz  = (orig & 7) * cpx + (orig >> 3);
    const int m0 = (swz / nwgx) * 128, n0 = (swz % nwgx) * 128;
    const int NKT = Kd >> 6;

    // staging source pointers (pre-swizzled chunk)
    const int sr = tid >> 3;             // 0..31
    const int sc = (tid & 7) ^ (sr & 7);
    const ushort* pA = A  + (size_t)(m0 + sr) * Kd + sc * 8;
    const ushort* pB = BT + (size_t)(n0 + sr) * Kd + sc * 8;

    f32x4 acc[4][4] = {};
    const int ca0 = (quad ^ rx) * 8;
    const int ca1 = ((4 + quad) ^ rx) * 8;

    // prologue: stage tile 0 into buf 0; drain, barrier.
    g13_stage(lds + wave*512,         pA, Kd);
    g13_stage(lds + 16384 + wave*512, pB, Kd);
    asm volatile("s_waitcnt vmcnt(0)" ::: "memory");
    __builtin_amdgcn_s_barrier();

    #pragma unroll 1
    for (int g = 0; g < NKT; ++g) {
        const ushort* Ab = lds + (g & 1) * 8192;
        const ushort* Bb = lds + 16384 + (g & 1) * 8192;

        // issue next-tile stages first (opposite buffer; clamp src at last)
        int nk = (g + 1 < NKT) ? g + 1 : NKT - 1;
        g13_stage(lds + ((g + 1) & 1) * 8192 + wave*512,         pA + nk*64, Kd);
        g13_stage(lds + 16384 + ((g + 1) & 1) * 8192 + wave*512, pB + nk*64, Kd);

        bf16x8 af[4][2], bf[4][2];
        #pragma unroll
        for (int i = 0; i < 4; ++i) {
            const ushort* p = Ab + (wr + i*16 + lr) * 64;
            af[i][0] = *reinterpret_cast<const bf16x8*>(p + ca0);
            af[i][1] = *reinterpret_cast<const bf16x8*>(p + ca1);
        }
        #pragma unroll
        for (int j = 0; j < 4; ++j) {
            const ushort* p = Bb + (wc + j*16 + lr) * 64;
            bf[j][0] = *reinterpret_cast<const bf16x8*>(p + ca0);
            bf[j][1] = *reinterpret_cast<const bf16x8*>(p + ca1);
        }
        __builtin_amdgcn_s_setprio(1);
        #pragma unroll
        for (int ks = 0; ks < 2; ++ks)
            #pragma unroll
            for (int i = 0; i < 4; ++i)
                #pragma unroll
                for (int j = 0; j < 4; ++j)
                    acc[i][j] = __builtin_amdgcn_mfma_f32_16x16x32_bf16(
                                    af[i][ks], bf[j][ks], acc[i][j], 0, 0, 0);
        __builtin_amdgcn_s_setprio(0);

        asm volatile("s_waitcnt vmcnt(0)" ::: "memory");
        __builtin_amdgcn_s_barrier();
    }

    #pragma unroll
    for (int i = 0; i < 4; ++i)
        #pragma unroll
        for (int j = 0; j < 4; ++j)
            #pragma unroll
            for (int r = 0; r < 4; ++r) {
                int row = m0 + wr + i*16 + quad*4 + r;      // m89-verified C/D map
                int col = n0 + wc + j*16 + lr;
                if (col < N)
                    C[(size_t)row * ldc + col] = acc[i][j][r];
            }
}

// ---------------------------------------------------------------------------
// Fused spectral+skip GEMM, single-phase pipelined + 2 blocks/CU (r3/r8/r9
// proven: ~147us, MfmaUtil 56%, VGPR 100). XCD swizzle REVERTED here (r10:
// FETCH 190->500 MB, dur 147->163 -- B-concat is 21 MB >> 4 MB L2, so
// per-XCD chunking makes each XCD stream B independently at uncorrelated
// phases, destroying the cross-XCD L3 reuse the default dispatch band gives).
// ---------------------------------------------------------------------------
#define G2NKT 36   // 24 k-tiles of summary (K=1536) + 12 of x (K=768)

__device__ __forceinline__ void g2_stageA(ushort* lds_, int kt,
                                          const ushort* pAs, const ushort* pAx,
                                          int wave, int part)
{
    int ktc = kt > (G2NKT-1) ? (G2NKT-1) : kt;   // clamp src; dest parity uses kt
    const ushort* g; size_t kd;
    if (ktc < 24) { g = pAs + ktc*64;      kd = 1536; }
    else          { g = pAx + (ktc-24)*64; kd = 768;  }
    g += (size_t)(part * 64) * kd;               // rows part*64 .. part*64+63
    ushort* d = lds_ + (kt & 1) * 8192 + part * 4096 + wave * 512;
    GLOAD16(g,           d);
    GLOAD16(g + 32*kd,   d + 2048);
}

__device__ __forceinline__ void g2_stageB(ushort* lds_, int kt,
                                          const ushort* pBs, const ushort* pBx,
                                          int wave)
{
    int ktc = kt > (G2NKT-1) ? (G2NKT-1) : kt;
    const ushort* g; size_t kd;
    if (ktc < 24) { g = pBs + ktc*64;      kd = 1536; }
    else          { g = pBx + (ktc-24)*64; kd = 768;  }
    ushort* d = lds_ + 16384 + (kt & 1) * 12288 + wave * 512;
    #pragma unroll
    for (int s = 0; s < 6; ++s)
        GLOAD16(g + (size_t)(32*s)*kd, d + 2048*s);
}

__global__ __launch_bounds__(256, 2)
void gemm2_1ph(const ushort* __restrict__ Sm, const ushort* __restrict__ Xb,
               const ushort* __restrict__ WsC, const ushort* __restrict__ WiC,
               ushort* __restrict__ yact)
{
    // LDS (ushort units): A bufs @0 and @8192 (128x64 each);
    //                     B bufs @16384 and @28672 (192x64 each). 80 KiB.
    __shared__ ushort lds[40960];
    const int tid  = threadIdx.x;
    const int lane = tid & 63, wave = tid >> 6;      // wave 0..3
    const int lr = lane & 15, quad = lane >> 4, rx = lr & 7;
    const int wr = (wave >> 1) * 64;     // 0,64
    const int wc = (wave & 1) * 96;      // 0,96
    const int m0 = blockIdx.y * 128, n0 = blockIdx.x * 192;

    // staging source pointers (pre-swizzled chunk): LDS[row][c] holds global
    // chunk c^(row&7); reader XORs the same way.
    const int sr = tid >> 3;             // 0..31
    const int sc = (tid & 7) ^ (sr & 7);
    const ushort* pAs = Sm  + (size_t)(m0 + sr) * 1536 + sc * 8;
    const ushort* pAx = Xb  + (size_t)(m0 + sr) * 768  + sc * 8;
    const ushort* pBs = WsC + (size_t)(n0 + sr) * 1536 + sc * 8;
    const ushort* pBx = WiC + (size_t)(n0 + sr) * 768  + sc * 8;

    f32x4 acc[4][6] = {};
    const int ca0 = (quad ^ rx) * 8;
    const int ca1 = ((4 + quad) ^ rx) * 8;

    // prologue: A(0) + B(0) = 10 loads; drain, barrier.
    g2_stageA(lds, 0, pAs, pAx, wave, 0);
    g2_stageA(lds, 0, pAs, pAx, wave, 1);
    g2_stageB(lds, 0, pBs, pBx, wave);
    asm volatile("s_waitcnt vmcnt(0)" ::: "memory");
    __builtin_amdgcn_s_barrier();

    #pragma unroll 1
    for (int g = 0; g < G2NKT; ++g) {
        const ushort* Ab = lds + (g & 1) * 8192;
        const ushort* Bb = lds + 16384 + (g & 1) * 12288;

        // issue next-tile stages first (max latency cover; opposite buffer)
        g2_stageA(lds, g + 1, pAs, pAx, wave, 0);
        g2_stageA(lds, g + 1, pAs, pAx, wave, 1);
        g2_stageB(lds, g + 1, pBs, pBx, wave);

        // fragments: compiler schedules ds_reads + fine-grained lgkm waits
        bf16x8 af[4][2], bfr[6][2];
        #pragma unroll
        for (int i = 0; i < 4; ++i) {
            const ushort* p = Ab + (wr + i*16 + lr) * 64;
            af[i][0] = *reinterpret_cast<const bf16x8*>(p + ca0);
            af[i][1] = *reinterpret_cast<const bf16x8*>(p + ca1);
        }
        #pragma unroll
        for (int j = 0; j < 6; ++j) {
            const ushort* p = Bb + (wc + j*16 + lr) * 64;
            bfr[j][0] = *reinterpret_cast<const bf16x8*>(p + ca0);
            bfr[j][1] = *reinterpret_cast<const bf16x8*>(p + ca1);
        }
        __builtin_amdgcn_s_setprio(1);
        #pragma unroll
        for (int ks = 0; ks < 2; ++ks)
            #pragma unroll
            for (int i = 0; i < 4; ++i)
                #pragma unroll
                for (int j = 0; j < 6; ++j)
                    acc[i][j] = __builtin_amdgcn_mfma_f32_16x16x32_bf16(
                                    af[i][ks], bfr[j][ks], acc[i][j], 0, 0, 0);
        __builtin_amdgcn_s_setprio(0);

        // drain next-tile stage (covered by the 48-MFMA burst), flip buffers
        asm volatile("s_waitcnt vmcnt(0)" ::: "memory");
        __builtin_amdgcn_s_barrier();
    }

    // epilogue: lane-local (val,gate) pairs -> gated SiLU -> bf16
    const int vg0 = (n0 + wc) >> 5;
    #pragma unroll
    for (int i = 0; i < 4; ++i)
        #pragma unroll
        for (int p = 0; p < 3; ++p)
            #pragma unroll
            for (int r = 0; r < 4; ++r) {
                int row = m0 + wr + i*16 + quad*4 + r;      // m89-verified C/D map
                int col = (vg0 + p)*16 + lr;
                float v  = acc[i][2*p][r];
                float gt = acc[i][2*p + 1][r];
                float y = v * (gt / (1.f + __expf(-gt)));
                yact[(size_t)row * NACT + col] = f2bf(y);
            }
}

// ---------------------------------------------------------------------------
// Fused token+scan pass 1: one block per (b,k,chunk), 128 thr = 2 waves.
// conv(CK=4)+SiLU+RMSNorm+phase + chunk partial sums; zmem read once
// (rolling-scalar window). r8/r9/r10-proven.
// ---------------------------------------------------------------------------
__global__ __launch_bounds__(128)
void token_scan1(const float* __restrict__ zmem, const float* __restrict__ conv_w,
                 const float* __restrict__ rms_scale, const float* __restrict__ theta_raw,
                 const float* __restrict__ dslopes, const float* __restrict__ sscale,
                 const float* __restrict__ tscale,
                 float* __restrict__ reN, float* __restrict__ imN,
                 float* __restrict__ pwN, float* __restrict__ part)
{
    int blk = blockIdx.x;            // = bk*16 + chunk
    int chunk = blk & (NCHUNK - 1);
    int bk = blk >> 4;
    int k = bk % K_;
    int b = bk / K_;
    int tid = threadIdx.x;
    int h = tid & 63;
    int tt = tid >> 6;               // wave -> token sub-range
    int l0 = chunk * CHLEN + tt * 64;

    int c  = k*H_ + h;
    int cs = DIM_MEM_ + k;

    // hoisted per-thread constants
    float cw0 = conv_w[0*DMK + c], cw1 = conv_w[1*DMK + c];
    float cw2 = conv_w[2*DMK + c], cw3 = conv_w[3*DMK + c];
    float cs0 = conv_w[0*DMK + cs], cs1 = conv_w[1*DMK + cs];
    float cs2 = conv_w[2*DMK + cs], cs3 = conv_w[3*DMK + cs];
    float rs  = rms_scale[h];
    float th  = 0.001f + 2.999f * (1.f / (1.f + __expf(-theta_raw[c])));
    float ts  = tscale[k];
    float scl = sscale[k];
    float slope = log1pf(expf(dslopes[k]));

    const float* zb = zmem + (size_t)(b*L_) * DMK;

    // rolling window carry: z3=row(l-3), z2=row(l-2), z1=row(l-1)
    float z3=0.f, z2=0.f, z1=0.f, s3=0.f, s2=0.f, s1=0.f;
    {
        int ll = l0 - 3;
        if (ll >= 0)     { z3 = zb[(size_t)ll*DMK + c];     s3 = zb[(size_t)ll*DMK + cs]; }
        if (ll + 1 >= 0) { z2 = zb[(size_t)(ll+1)*DMK + c]; s2 = zb[(size_t)(ll+1)*DMK + cs]; }
        if (ll + 2 >= 0) { z1 = zb[(size_t)(ll+2)*DMK + c]; s1 = zb[(size_t)(ll+2)*DMK + cs]; }
    }

    float sre = 0.f, sim = 0.f, spw = 0.f;
    size_t obase = (size_t)blk * (CHLEN*H_) + (size_t)(tt*64)*H_ + h;

    for (int i0 = 0; i0 < 64; i0 += 8) {
        float zl[8], sl[8];
        #pragma unroll
        for (int j = 0; j < 8; ++j) {
            int l = l0 + i0 + j;
            zl[j] = zb[(size_t)l*DMK + c];
            sl[j] = zb[(size_t)l*DMK + cs];
        }
        #pragma unroll
        for (int j = 0; j < 8; ++j) {
            int l = l0 + i0 + j;
            float a3 = zl[j], b3 = sl[j];
            float acc  = cw0*z3 + cw1*z2 + cw2*z1 + cw3*a3;
            float acc2 = cs0*s3 + cs1*s2 + cs2*s1 + cs3*b3;
            z3 = z2; z2 = z1; z1 = a3;       // roll the windows (pure scalars)
            s3 = s2; s2 = s1; s1 = b3;

            float kv = acc / (1.f + __expf(-acc));          // silu (hw exp)
            float ss = kv * kv;
            #pragma unroll
            for (int off = 32; off > 0; off >>= 1)
                ss += __shfl_xor(ss, off, 64);
            float kn  = kv * rsqrtf(ss * (1.f/64.f) + 1e-6f) * rs;
            float phi = tanh_fast(kn * ts) * th;

            float s  = acc2 / (1.f + expf(-acc2));          // match original expf
            float lp = fminf(10.f, fmaxf(-10.f, scl * s));
            float pwv = expf(lp - slope * (float)(L_ - 1 - l));

            float kvw = kn * pwv;
            float rev = kvw * __cosf(phi);
            float imv = kvw * __sinf(phi);
            reN[obase + (size_t)(i0 + j)*H_] = rev;
            imN[obase + (size_t)(i0 + j)*H_] = imv;
            sre += rev; sim += imv; spw += pwv;
            if (h == 0) pwN[(size_t)bk * L_ + l] = pwv;
        }
    }

    // cross-wave combine -> chunk partials (same layout as old scan_sums)
    __shared__ float red[2][64], imd[2][64], pwd[2];
    red[tt][h] = sre; imd[tt][h] = sim;
    if (h == 0) pwd[tt] = spw;
    __syncthreads();
    size_t pb = (size_t)blk * PSTRIDE;
    if (tid < 64) part[pb + tid] = red[0][tid] + red[1][tid];
    else          part[pb + tid] = imd[0][tid - 64] + imd[1][tid - 64];
    if (tid == 0) part[pb + 128] = pwd[0] + pwd[1];
}

// ---------------------------------------------------------------------------
// Scan pass 2 on the chunk-local layout: prefix from partials, emit bf16
// summary. Identical accumulation order to the old scan_final. r8-r10 proven.
// ---------------------------------------------------------------------------
__global__ __launch_bounds__(128)
void scan_final2(const float* __restrict__ pwN, const float* __restrict__ reN,
                 const float* __restrict__ imN, const float* __restrict__ part,
                 ushort* __restrict__ summary)
{
    int blk = blockIdx.x;
    int chunk = blk & (NCHUNK - 1);
    int bk = blk >> 4;
    int k = bk % K_;
    int b = bk / K_;
    int tid = threadIdx.x;
    int h = tid & 63;
    int pi = tid >> 6;
    const float* __restrict__ src = pi ? imN : reN;
    int l0 = chunk * CHLEN;

    float acc = 0.f, dacc = 0.f;
    size_t pb0 = (size_t)(bk * NCHUNK) * PSTRIDE;
    for (int cn = 0; cn < chunk; ++cn) {
        acc  += part[pb0 + (size_t)cn*PSTRIDE + tid];
        dacc += part[pb0 + (size_t)cn*PSTRIDE + 128];
    }

    size_t base  = (size_t)blk * (CHLEN*H_) + h;
    size_t dbase = (size_t)bk * L_ + l0;
    int outch = 2*(k*H_ + h) + pi;
    for (int i0 = 0; i0 < CHLEN; i0 += 8) {
        float v[8], d[8];
        #pragma unroll
        for (int j = 0; j < 8; ++j) {
            v[j] = src[base + (size_t)(i0 + j)*H_];
            d[j] = pwN[dbase + i0 + j];
        }
        #pragma unroll
        for (int j = 0; j < 8; ++j) {
            acc += v[j]; dacc += d[j];
            float inv = 1.f / fmaxf(dacc, 1e-4f);
            summary[((size_t)(b*L_ + l0 + i0 + j))*NSUM + outch] = f2bf(acc * inv);
        }
    }
}

// ---------------------------------------------------------------------------
extern "C" void kernel_launch(void* const* d_in, const int* in_sizes, int n_in,
                              void* d_out, int out_size, void* d_ws, size_t ws_size,
                              hipStream_t stream)
{
    const float* x         = (const float*)d_in[0];
    const float* W_in      = (const float*)d_in[1];
    const float* conv_w    = (const float*)d_in[2];
    const float* rms_scale = (const float*)d_in[3];
    const float* theta_raw = (const float*)d_in[4];
    const float* dslopes   = (const float*)d_in[5];
    const float* sscale    = (const float*)d_in[6];
    const float* tscale    = (const float*)d_in[7];
    const float* W_sw      = (const float*)d_in[8];
    const float* W_out     = (const float*)d_in[9];
    float* out = (float*)d_out;
    char* ws   = (char*)d_ws;

    // Workspace (byte offsets, all 256-aligned). Peak ~115.4 MB (< proven 127).
    float*  zmem    = (float*) (ws + 0);           // NT*780 f32   = 25,559,040 B
    ushort* summary = (ushort*)(ws + 0);           // alias (zmem dead): 25,165,824 B
    float*  pw      = (float*) (ws + 25559040);    //   393,216 B  [bk][l]
    float*  re      = (float*) (ws + 25952256);    // 25,165,824 B [blk][tok][h]
    float*  im      = (float*) (ws + 51118080);    // 25,165,824 B
    ushort* yact    = (ushort*)(ws + 25952256);    // alias re+im (dead): 37,748,736 B
    float*  part    = (float*) (ws + 76283904);    //   405,504 B
    ushort* xb      = (ushort*)(ws + 76689408);    // 12,582,912 B
    ushort* WiCat   = (ushort*)(ws + 89272320);    //  7,077,888 B  [4608][768]  val/gate interleaved
    ushort* WsCat   = (ushort*)(ws + 96350208);    // 14,155,776 B  [4608][1536] val/gate interleaved
    ushort* WoT     = (ushort*)(ws + 110505984);   //  3,538,944 B  [768][2304]
    ushort* WimT    = (ushort*)(ws + 114044928);   //  1,376,256 B  [896][768] (pad)

    // ---- merged prep job table ----
    PrepJobs J{};
    J.W[0]=W_in;  J.out[0]=WiCat; J.ldw[0]=5388; J.Kd[0]=768;  J.colbase[0]=780; J.remap[0]=1; J.ntx[0]=144;
    J.W[1]=W_sw;  J.out[1]=WsCat; J.ldw[1]=4608; J.Kd[1]=1536; J.colbase[1]=0;   J.remap[1]=1; J.ntx[1]=144;
    J.W[2]=W_out; J.out[2]=WoT;   J.ldw[2]=768;  J.Kd[2]=2304; J.colbase[2]=0;   J.remap[2]=0; J.ntx[2]=24;
    J.W[3]=W_in;  J.out[3]=WimT;  J.ldw[3]=5388; J.Kd[3]=768;  J.colbase[3]=0;   J.remap[3]=0; J.ntx[3]=28;
    int tiles[4] = {144*24, 144*48, 24*72, 28*24};
    J.start[0] = 0;
    for (int j = 0; j < 4; ++j) J.start[j+1] = J.start[j] + tiles[j];
    J.start[5] = J.start[4];
    J.start[6] = J.start[4];
    J.cast_in = x; J.cast_out = xb; J.n4 = NT*D_/4;
    int nblk = J.start[6] + (J.n4 + 255)/256;

    dim3 blk(256);
    // 0) all preps in one launch
    prep_all<<<dim3(nblk), blk, 0, stream>>>(J);
    // 1) z_mem = x @ W_in[:, :780]  (1-phase pipelined MFMA + XCD swizzle)
    gemm13_1ph<<<dim3(7, 64), blk, 0, stream>>>(xb, WimT, zmem, 768, 780, 780);
    // 2) fused conv+silu+rmsnorm+phase + chunk partial sums (1x zmem read)
    token_scan1<<<dim3(B_*K_*NCHUNK), dim3(128), 0, stream>>>(
        zmem, conv_w, rms_scale, theta_raw, dslopes, sscale, tscale,
        re, im, pw, part);
    // 3) prefix + emit summary (bf16)
    scan_final2<<<dim3(B_*K_*NCHUNK), dim3(128), 0, stream>>>(pw, re, im, part, summary);
    // 4) fused spectral+skip single-phase pipelined GEMM (no swizzle) -> yact
    gemm2_1ph<<<dim3(24, 64), dim3(256), 0, stream>>>(summary, xb, WsCat, WiCat, yact);
    // 5) out = yact @ W_out  (1-phase pipelined MFMA + XCD swizzle)
    gemm13_1ph<<<dim3(6, 64), blk, 0, stream>>>(yact, WoT, out, 2304, 768, 768);
}